// Round 1
// baseline (1230.977 us; speedup 1.0000x reference)
//
#include <hip/hip_runtime.h>
#include <math.h>

#define NEG_SLOPE 0.2f
#define GAT_EPS 1e-16f

__device__ __forceinline__ float elu_f(float x) { return x > 0.f ? x : expm1f(x); }
__device__ __forceinline__ float lrelu_f(float x) { return x > 0.f ? x : NEG_SLOPE * x; }
__device__ __forceinline__ float neg_inf_f() { return __int_as_float(0xFF800000); }

__device__ __forceinline__ void atomicMaxFloat(float* addr, float val) {
    // sign-magnitude trick; buffer initialized to -inf
    if (val >= 0.f) atomicMax((int*)addr, __float_as_int(val));
    else            atomicMin((unsigned int*)addr, __float_as_uint(val));
}

__device__ __forceinline__ float waveReduceSum(float v) {
    #pragma unroll
    for (int off = 32; off > 0; off >>= 1) v += __shfl_xor(v, off, 64);
    return v;
}

// ---------------- init ----------------
__global__ void init_main(float* g1, float* g2, float* sums, float* cnts,
                          float* emax, float* denom, int N, int G) {
    int i = blockIdx.x * 256 + threadIdx.x;
    if (i < N * 64)  g1[i] = 0.f;
    if (i < N * 128) g2[i] = 0.f;
    if (i < G * 128) sums[i] = 0.f;
    if (i < G)       cnts[i] = 0.f;
    if (i < N * 2)  { emax[i] = neg_inf_f(); denom[i] = 0.f; }
}

__global__ void init_layer(float* emax, float* denom, int M) {
    int i = blockIdx.x * 256 + threadIdx.x;
    if (i < M) { emax[i] = neg_inf_f(); denom[i] = 0.f; }
}

// ---------------- fc0: h0 = elu(x @ W + b), x[N,16], W[16,32] ----------------
__global__ __launch_bounds__(256) void fc0_kernel(
        const float* __restrict__ x, const float* __restrict__ w,
        const float* __restrict__ b, float* __restrict__ h0, int N) {
    __shared__ float xs[8 * 16];
    int n0 = blockIdx.x * 8;
    int tid = threadIdx.x;
    if (tid < 128) {
        int gi = n0 * 16 + tid;
        xs[tid] = (gi < N * 16) ? x[gi] : 0.f;
    }
    __syncthreads();
    int j = tid >> 5, o = tid & 31;
    int n = n0 + j;
    float acc = b[o];
    #pragma unroll
    for (int c = 0; c < 16; ++c) acc = fmaf(xs[j * 16 + c], w[c * 32 + o], acc);
    if (n < N) h0[n * 32 + o] = elu_f(acc);
}

// ---------------- GAT layer1 transform: h1[N,2,64] = h0 @ W1; e_src/e_dst ----------------
// block 128 threads = (head = tid>>6, o = tid&63), 8 nodes per block
__global__ __launch_bounds__(128) void gat_transform1(
        const float* __restrict__ h0, const float* __restrict__ W,
        const float* __restrict__ asrc, const float* __restrict__ adst,
        float* __restrict__ h1, float* __restrict__ es, float* __restrict__ ed, int N) {
    __shared__ float xs[8 * 32];
    int n0 = blockIdx.x * 8;
    int tid = threadIdx.x;
    for (int idx = tid; idx < 8 * 32; idx += 128) {
        int gi = n0 * 32 + idx;
        xs[idx] = (gi < N * 32) ? h0[gi] : 0.f;
    }
    __syncthreads();
    int h = tid >> 6, lane = tid & 63, o = lane;
    float acc[8];
    #pragma unroll
    for (int j = 0; j < 8; ++j) acc[j] = 0.f;
    const float* wp = W + h * (32 * 64) + o;
    #pragma unroll
    for (int c = 0; c < 32; ++c) {
        float wv = wp[c * 64];
        #pragma unroll
        for (int j = 0; j < 8; ++j) acc[j] = fmaf(xs[j * 32 + c], wv, acc[j]);
    }
    float as = asrc[h * 64 + o], ad = adst[h * 64 + o];
    for (int j = 0; j < 8; ++j) {
        int n = n0 + j;
        if (n < N) h1[(size_t)n * 128 + tid] = acc[j];
        float vs = waveReduceSum(acc[j] * as);
        float vd = waveReduceSum(acc[j] * ad);
        if (lane == 0 && n < N) { es[n * 2 + h] = vs; ed[n * 2 + h] = vd; }
    }
}

// ---------------- GAT layer2 transform: h2[N,2,128] = elu(g1+b1) @ W2 ----------------
// block 256 threads = (head = tid>>7, o = tid&127), 8 nodes per block
__global__ __launch_bounds__(256) void gat_transform2(
        const float* __restrict__ g1, const float* __restrict__ b1,
        const float* __restrict__ W, const float* __restrict__ asrc,
        const float* __restrict__ adst, float* __restrict__ h2,
        float* __restrict__ es, float* __restrict__ ed, int N) {
    __shared__ float xs[8 * 64];
    __shared__ float esl[16], edl[16];
    int n0 = blockIdx.x * 8;
    int tid = threadIdx.x;
    for (int idx = tid; idx < 8 * 64; idx += 256) {
        int gi = n0 * 64 + idx;
        float v = (gi < N * 64) ? g1[gi] : 0.f;
        xs[idx] = elu_f(v + b1[idx & 63]);
    }
    if (tid < 16) { esl[tid] = 0.f; edl[tid] = 0.f; }
    __syncthreads();
    int h = tid >> 7, o = tid & 127, lane = tid & 63;
    float acc[8];
    #pragma unroll
    for (int j = 0; j < 8; ++j) acc[j] = 0.f;
    const float* wp = W + h * (64 * 128) + o;
    for (int c = 0; c < 64; ++c) {
        float wv = wp[c * 128];
        #pragma unroll
        for (int j = 0; j < 8; ++j) acc[j] = fmaf(xs[j * 64 + c], wv, acc[j]);
    }
    float as = asrc[h * 128 + o], ad = adst[h * 128 + o];
    #pragma unroll
    for (int j = 0; j < 8; ++j) {
        int n = n0 + j;
        if (n < N) h2[(size_t)n * 256 + tid] = acc[j];
        float vs = waveReduceSum(acc[j] * as);
        float vd = waveReduceSum(acc[j] * ad);
        if (lane == 0) { atomicAdd(&esl[j * 2 + h], vs); atomicAdd(&edl[j * 2 + h], vd); }
    }
    __syncthreads();
    if (tid < 16) {
        int j = tid >> 1, hh = tid & 1, n = n0 + j;
        if (n < N) { es[n * 2 + hh] = esl[tid]; ed[n * 2 + hh] = edl[tid]; }
    }
}

// ---------------- edge pass A: e = lrelu(es[src]+ed[dst]); segment max over dst ----------------
__global__ __launch_bounds__(256) void edge_emax(
        const int* __restrict__ src, const int* __restrict__ dst,
        const float* __restrict__ es, const float* __restrict__ ed,
        float* __restrict__ ew, float* __restrict__ emax, int E) {
    int e = blockIdx.x * 256 + threadIdx.x;
    if (e >= E) return;
    int s = src[e], d = dst[e];
    float2 esv = *reinterpret_cast<const float2*>(es + (size_t)s * 2);
    float2 edv = *reinterpret_cast<const float2*>(ed + (size_t)d * 2);
    float e0 = lrelu_f(esv.x + edv.x);
    float e1 = lrelu_f(esv.y + edv.y);
    float2 ev; ev.x = e0; ev.y = e1;
    *reinterpret_cast<float2*>(ew + (size_t)e * 2) = ev;
    atomicMaxFloat(&emax[d * 2], e0);
    atomicMaxFloat(&emax[d * 2 + 1], e1);
}

// ---------------- edge pass B: w = exp(e - emax[dst]); segment sum over dst ----------------
__global__ __launch_bounds__(256) void edge_expsum(
        const int* __restrict__ dst, const float* __restrict__ emax,
        float* __restrict__ ew, float* __restrict__ denom, int E) {
    int e = blockIdx.x * 256 + threadIdx.x;
    if (e >= E) return;
    int d = dst[e];
    float2 mv = *reinterpret_cast<const float2*>(emax + (size_t)d * 2);
    float2 ev = *reinterpret_cast<const float2*>(ew + (size_t)e * 2);
    float w0 = __expf(ev.x - mv.x);
    float w1 = __expf(ev.y - mv.y);
    float2 wv; wv.x = w0; wv.y = w1;
    *reinterpret_cast<float2*>(ew + (size_t)e * 2) = wv;
    atomicAdd(&denom[d * 2], w0);
    atomicAdd(&denom[d * 2 + 1], w1);
}

// ---------------- edge pass C: g[dst] += 0.5 * sum_h alpha_h * h[src,h,:] ----------------
// layer1: C=64, block 256 = 4 edges x 64 lanes
__global__ __launch_bounds__(256) void edge_message1(
        const int* __restrict__ src, const int* __restrict__ dst,
        const float* __restrict__ ew, const float* __restrict__ denom,
        const float* __restrict__ h1, float* __restrict__ g1, int E) {
    int e = blockIdx.x * 4 + (threadIdx.x >> 6);
    int o = threadIdx.x & 63;
    if (e >= E) return;
    int s = src[e], d = dst[e];
    float2 wv = *reinterpret_cast<const float2*>(ew + (size_t)e * 2);
    float2 dn = *reinterpret_cast<const float2*>(denom + (size_t)d * 2);
    float a0 = 0.5f * wv.x / (dn.x + GAT_EPS);
    float a1 = 0.5f * wv.y / (dn.y + GAT_EPS);
    const float* hp = h1 + (size_t)s * 128;
    float v = a0 * hp[o] + a1 * hp[64 + o];
    atomicAdd(&g1[(size_t)d * 64 + o], v);
}

// layer2: C=128, block 256 = 2 edges x 128 lanes
__global__ __launch_bounds__(256) void edge_message2(
        const int* __restrict__ src, const int* __restrict__ dst,
        const float* __restrict__ ew, const float* __restrict__ denom,
        const float* __restrict__ h2, float* __restrict__ g2, int E) {
    int e = blockIdx.x * 2 + (threadIdx.x >> 7);
    int o = threadIdx.x & 127;
    if (e >= E) return;
    int s = src[e], d = dst[e];
    float2 wv = *reinterpret_cast<const float2*>(ew + (size_t)e * 2);
    float2 dn = *reinterpret_cast<const float2*>(denom + (size_t)d * 2);
    float a0 = 0.5f * wv.x / (dn.x + GAT_EPS);
    float a1 = 0.5f * wv.y / (dn.y + GAT_EPS);
    const float* hp = h2 + (size_t)s * 256;
    float v = a0 * hp[o] + a1 * hp[128 + o];
    atomicAdd(&g2[(size_t)d * 128 + o], v);
}

// ---------------- pool: sums[batch[n]] += elu(g2[n]+b2); cnts[batch[n]] += 1 ----------------
__global__ __launch_bounds__(256) void pool_kernel(
        const float* __restrict__ g2, const float* __restrict__ b2,
        const int* __restrict__ batch, float* __restrict__ sums,
        float* __restrict__ cnts, int N) {
    int idx = blockIdx.x * 256 + threadIdx.x;
    if (idx >= N * 128) return;
    int n = idx >> 7, c = idx & 127;
    int b = batch[n];
    float v = elu_f(g2[idx] + b2[c]);
    atomicAdd(&sums[(size_t)b * 128 + c], v);
    if (c == 0) atomicAdd(&cnts[b], 1.f);
}

// ---------------- final: out = (sums/cnt) @ lo_w + lo_b ----------------
__global__ void final_kernel(
        const float* __restrict__ sums, const float* __restrict__ cnts,
        const float* __restrict__ w, const float* __restrict__ b,
        float* __restrict__ out, int G) {
    int g = blockIdx.x;
    int k = threadIdx.x;
    if (k >= 24) return;
    float inv = 1.f / fmaxf(cnts[g], 1.f);
    float acc = b[k];
    #pragma unroll
    for (int c = 0; c < 128; ++c) acc = fmaf(sums[g * 128 + c] * inv, w[c * 24 + k], acc);
    out[g * 24 + k] = acc;
}

extern "C" void kernel_launch(void* const* d_in, const int* in_sizes, int n_in,
                              void* d_out, int out_size, void* d_ws, size_t ws_size,
                              hipStream_t stream) {
    const float* x      = (const float*)d_in[0];
    const int*   ei     = (const int*)d_in[1];
    const int*   batch  = (const int*)d_in[2];
    const float* fc0_w  = (const float*)d_in[3];
    const float* fc0_b  = (const float*)d_in[4];
    const float* W1     = (const float*)d_in[5];
    const float* a_src1 = (const float*)d_in[6];
    const float* a_dst1 = (const float*)d_in[7];
    const float* b1     = (const float*)d_in[8];
    const float* W2     = (const float*)d_in[9];
    const float* a_src2 = (const float*)d_in[10];
    const float* a_dst2 = (const float*)d_in[11];
    const float* b2     = (const float*)d_in[12];
    const float* lo_w   = (const float*)d_in[13];
    const float* lo_b   = (const float*)d_in[14];
    float* out = (float*)d_out;

    const int N = in_sizes[0] / 16;
    const int E = in_sizes[1] / 2;
    const int G = out_size / 24;
    const int* src = ei;
    const int* dst = ei + E;

    float* ws = (float*)d_ws;
    size_t off = 0;
    auto alloc = [&](size_t n) { float* p = ws + off; off += (n + 63) & ~(size_t)63; return p; };
    float* h0    = alloc((size_t)N * 32);
    float* hbuf  = alloc((size_t)N * 256);   // h1 uses N*128 of it; h2 uses N*256
    float* g1    = alloc((size_t)N * 64);
    float* g2    = alloc((size_t)N * 128);
    float* es    = alloc((size_t)N * 2);
    float* ed    = alloc((size_t)N * 2);
    float* emax  = alloc((size_t)N * 2);
    float* denom = alloc((size_t)N * 2);
    float* ew    = alloc((size_t)E * 2);
    float* sums  = alloc((size_t)G * 128);
    float* cnts  = alloc((size_t)G);
    (void)ws_size;

    // init (g1, g2, sums, cnts zero; emax=-inf, denom=0 for layer 1)
    init_main<<<(N * 128 + 255) / 256, 256, 0, stream>>>(g1, g2, sums, cnts, emax, denom, N, G);

    // fc0
    fc0_kernel<<<(N + 7) / 8, 256, 0, stream>>>(x, fc0_w, fc0_b, h0, N);

    // ---- GAT layer 1 ----
    gat_transform1<<<(N + 7) / 8, 128, 0, stream>>>(h0, W1, a_src1, a_dst1, hbuf, es, ed, N);
    edge_emax  <<<(E + 255) / 256, 256, 0, stream>>>(src, dst, es, ed, ew, emax, E);
    edge_expsum<<<(E + 255) / 256, 256, 0, stream>>>(dst, emax, ew, denom, E);
    edge_message1<<<(E + 3) / 4, 256, 0, stream>>>(src, dst, ew, denom, hbuf, g1, E);

    // ---- GAT layer 2 ----
    init_layer<<<(N * 2 + 255) / 256, 256, 0, stream>>>(emax, denom, N * 2);
    gat_transform2<<<(N + 7) / 8, 256, 0, stream>>>(g1, b1, W2, a_src2, a_dst2, hbuf, es, ed, N);
    edge_emax  <<<(E + 255) / 256, 256, 0, stream>>>(src, dst, es, ed, ew, emax, E);
    edge_expsum<<<(E + 255) / 256, 256, 0, stream>>>(dst, emax, ew, denom, E);
    edge_message2<<<(E + 1) / 2, 256, 0, stream>>>(src, dst, ew, denom, hbuf, g2, E);

    // ---- pool + final linear ----
    pool_kernel<<<(N * 128 + 255) / 256, 256, 0, stream>>>(g2, b2, batch, sums, cnts, N);
    final_kernel<<<G, 32, 0, stream>>>(sums, cnts, lo_w, lo_b, out, G);
}

// Round 2
// 728.599 us; speedup vs baseline: 1.6895x; 1.6895x over previous
//
#include <hip/hip_runtime.h>
#include <math.h>

#define NEG_SLOPE 0.2f
#define GAT_EPS 1e-16f

__device__ __forceinline__ float elu_f(float x) { return x > 0.f ? x : expm1f(x); }
__device__ __forceinline__ float lrelu_f(float x) { return x > 0.f ? x : NEG_SLOPE * x; }
__device__ __forceinline__ float neg_inf_f() { return __int_as_float(0xFF800000); }

__device__ __forceinline__ float waveReduceSum(float v) {
    #pragma unroll
    for (int off = 32; off > 0; off >>= 1) v += __shfl_xor(v, off, 64);
    return v;
}

// ---------------- init: zero deg, sums, cnts ----------------
__global__ void init_kernel(int* deg, float* sums, float* cnts, int N, int G) {
    int i = blockIdx.x * 256 + threadIdx.x;
    if (i < N) deg[i] = 0;
    if (i < G * 128) sums[i] = 0.f;
    if (i < G) cnts[i] = 0.f;
}

// ---------------- CSR build ----------------
__global__ __launch_bounds__(256) void hist_kernel(const int* __restrict__ dst,
                                                   int* __restrict__ deg, int E) {
    int e = blockIdx.x * 256 + threadIdx.x;
    if (e < E) atomicAdd(&deg[dst[e]], 1);
}

// single-block exclusive scan over N elements (N up to ~several 100k fine)
__global__ __launch_bounds__(1024) void scan_kernel(const int* __restrict__ deg,
        int* __restrict__ ofs, int* __restrict__ cursor, int N) {
    __shared__ int wsum[16];
    __shared__ int carry_s;
    int tid = threadIdx.x;
    int lane = tid & 63, wid = tid >> 6;
    if (tid == 0) carry_s = 0;
    __syncthreads();
    for (int base = 0; base < N; base += 1024) {
        int i = base + tid;
        int v = (i < N) ? deg[i] : 0;
        int incl = v;
        #pragma unroll
        for (int off = 1; off < 64; off <<= 1) {
            int t = __shfl_up(incl, off, 64);
            if (lane >= off) incl += t;
        }
        if (lane == 63) wsum[wid] = incl;
        __syncthreads();
        if (wid == 0) {
            int wv = (lane < 16) ? wsum[lane] : 0;
            int winc = wv;
            #pragma unroll
            for (int off = 1; off < 16; off <<= 1) {
                int t = __shfl_up(winc, off, 64);
                if (lane >= off) winc += t;
            }
            if (lane < 16) wsum[lane] = winc - wv;  // exclusive wave offset
        }
        __syncthreads();
        int excl = incl - v + wsum[wid] + carry_s;
        if (i < N) { ofs[i] = excl; cursor[i] = excl; }
        __syncthreads();
        if (tid == 1023) carry_s = excl + v;
        __syncthreads();
    }
    if (tid == 0) ofs[N] = carry_s;
}

__global__ __launch_bounds__(256) void scatter_kernel(
        const int* __restrict__ src, const int* __restrict__ dst,
        int* __restrict__ cursor, int* __restrict__ sperm, int E) {
    int e = blockIdx.x * 256 + threadIdx.x;
    if (e >= E) return;
    int d = dst[e];
    int pos = atomicAdd(&cursor[d], 1);
    sperm[pos] = src[e];
}

// ---------------- fc0: h0 = elu(x @ W + b), x[N,16], W[16,32] ----------------
__global__ __launch_bounds__(256) void fc0_kernel(
        const float* __restrict__ x, const float* __restrict__ w,
        const float* __restrict__ b, float* __restrict__ h0, int N) {
    __shared__ float xs[8 * 16];
    int n0 = blockIdx.x * 8;
    int tid = threadIdx.x;
    if (tid < 128) {
        int gi = n0 * 16 + tid;
        xs[tid] = (gi < N * 16) ? x[gi] : 0.f;
    }
    __syncthreads();
    int j = tid >> 5, o = tid & 31;
    int n = n0 + j;
    float acc = b[o];
    #pragma unroll
    for (int c = 0; c < 16; ++c) acc = fmaf(xs[j * 16 + c], w[c * 32 + o], acc);
    if (n < N) h0[n * 32 + o] = elu_f(acc);
}

// ---------------- GAT layer1 transform: h1[N,2,64] = h0 @ W1; e_src/e_dst ----------------
__global__ __launch_bounds__(128) void gat_transform1(
        const float* __restrict__ h0, const float* __restrict__ W,
        const float* __restrict__ asrc, const float* __restrict__ adst,
        float* __restrict__ h1, float* __restrict__ es, float* __restrict__ ed, int N) {
    __shared__ float xs[8 * 32];
    int n0 = blockIdx.x * 8;
    int tid = threadIdx.x;
    for (int idx = tid; idx < 8 * 32; idx += 128) {
        int gi = n0 * 32 + idx;
        xs[idx] = (gi < N * 32) ? h0[gi] : 0.f;
    }
    __syncthreads();
    int h = tid >> 6, lane = tid & 63, o = lane;
    float acc[8];
    #pragma unroll
    for (int j = 0; j < 8; ++j) acc[j] = 0.f;
    const float* wp = W + h * (32 * 64) + o;
    #pragma unroll
    for (int c = 0; c < 32; ++c) {
        float wv = wp[c * 64];
        #pragma unroll
        for (int j = 0; j < 8; ++j) acc[j] = fmaf(xs[j * 32 + c], wv, acc[j]);
    }
    float as = asrc[h * 64 + o], ad = adst[h * 64 + o];
    for (int j = 0; j < 8; ++j) {
        int n = n0 + j;
        if (n < N) h1[(size_t)n * 128 + tid] = acc[j];
        float vs = waveReduceSum(acc[j] * as);
        float vd = waveReduceSum(acc[j] * ad);
        if (lane == 0 && n < N) { es[n * 2 + h] = vs; ed[n * 2 + h] = vd; }
    }
}

// ---------------- GAT layer2 transform: h2[N,2,128] = elu(g1+b1) @ W2 ----------------
__global__ __launch_bounds__(256) void gat_transform2(
        const float* __restrict__ g1, const float* __restrict__ b1,
        const float* __restrict__ W, const float* __restrict__ asrc,
        const float* __restrict__ adst, float* __restrict__ h2,
        float* __restrict__ es, float* __restrict__ ed, int N) {
    __shared__ float xs[8 * 64];
    __shared__ float esl[16], edl[16];
    int n0 = blockIdx.x * 8;
    int tid = threadIdx.x;
    for (int idx = tid; idx < 8 * 64; idx += 256) {
        int gi = n0 * 64 + idx;
        float v = (gi < N * 64) ? g1[gi] : 0.f;
        xs[idx] = elu_f(v + b1[idx & 63]);
    }
    if (tid < 16) { esl[tid] = 0.f; edl[tid] = 0.f; }
    __syncthreads();
    int h = tid >> 7, o = tid & 127, lane = tid & 63;
    float acc[8];
    #pragma unroll
    for (int j = 0; j < 8; ++j) acc[j] = 0.f;
    const float* wp = W + h * (64 * 128) + o;
    for (int c = 0; c < 64; ++c) {
        float wv = wp[c * 128];
        #pragma unroll
        for (int j = 0; j < 8; ++j) acc[j] = fmaf(xs[j * 64 + c], wv, acc[j]);
    }
    float as = asrc[h * 128 + o], ad = adst[h * 128 + o];
    #pragma unroll
    for (int j = 0; j < 8; ++j) {
        int n = n0 + j;
        if (n < N) h2[(size_t)n * 256 + tid] = acc[j];
        float vs = waveReduceSum(acc[j] * as);
        float vd = waveReduceSum(acc[j] * ad);
        if (lane == 0) { atomicAdd(&esl[j * 2 + h], vs); atomicAdd(&edl[j * 2 + h], vd); }
    }
    __syncthreads();
    if (tid < 16) {
        int j = tid >> 1, hh = tid & 1, n = n0 + j;
        if (n < N) { es[n * 2 + hh] = esl[tid]; ed[n * 2 + hh] = edl[tid]; }
    }
}

// ---------------- aggregation layer1: one wave per dst node ----------------
// g1[d, 0..63] = 0.5 * sum_h sum_{e in in(d)} alpha_eh * h1[src_e, h, :]
__global__ __launch_bounds__(256) void gat_agg1(
        const int* __restrict__ ofs, const int* __restrict__ sperm,
        const float* __restrict__ es, const float* __restrict__ ed,
        const float* __restrict__ h1, float* __restrict__ g1, int N) {
    int d = blockIdx.x * 4 + (threadIdx.x >> 6);
    if (d >= N) return;
    int lane = threadIdx.x & 63;
    int beg = ofs[d], end = ofs[d + 1];
    int deg = end - beg;
    float2 edv = *reinterpret_cast<const float2*>(ed + (size_t)d * 2);

    // stats: per-lane first edge cached in regs
    int s_f = 0;
    float e0f = neg_inf_f(), e1f = neg_inf_f();
    float m0 = neg_inf_f(), m1 = neg_inf_f();
    int i0 = beg + lane;
    if (i0 < end) {
        s_f = sperm[i0];
        float2 esv = *reinterpret_cast<const float2*>(es + (size_t)s_f * 2);
        e0f = lrelu_f(esv.x + edv.x);
        e1f = lrelu_f(esv.y + edv.y);
        m0 = e0f; m1 = e1f;
    }
    for (int i = i0 + 64; i < end; i += 64) {
        int s = sperm[i];
        float2 esv = *reinterpret_cast<const float2*>(es + (size_t)s * 2);
        m0 = fmaxf(m0, lrelu_f(esv.x + edv.x));
        m1 = fmaxf(m1, lrelu_f(esv.y + edv.y));
    }
    #pragma unroll
    for (int off = 32; off > 0; off >>= 1) {
        m0 = fmaxf(m0, __shfl_xor(m0, off, 64));
        m1 = fmaxf(m1, __shfl_xor(m1, off, 64));
    }
    float s0 = 0.f, s1 = 0.f;
    if (i0 < end) { s0 = __expf(e0f - m0); s1 = __expf(e1f - m1); }
    for (int i = i0 + 64; i < end; i += 64) {
        int s = sperm[i];
        float2 esv = *reinterpret_cast<const float2*>(es + (size_t)s * 2);
        s0 += __expf(lrelu_f(esv.x + edv.x) - m0);
        s1 += __expf(lrelu_f(esv.y + edv.y) - m1);
    }
    s0 = waveReduceSum(s0);
    s1 = waveReduceSum(s1);
    float r0 = 0.5f / (s0 + GAT_EPS), r1 = 0.5f / (s1 + GAT_EPS);
    float a0f = __expf(e0f - m0) * r0;   // valid where lane < deg
    float a1f = __expf(e1f - m1) * r1;

    float acc = 0.f;
    int o = lane;
    int jmax = deg < 64 ? deg : 64;
    for (int j = 0; j < jmax; ++j) {
        int s = __shfl(s_f, j, 64);
        float a0 = __shfl(a0f, j, 64);
        float a1 = __shfl(a1f, j, 64);
        const float* hp = h1 + (size_t)s * 128;
        acc += a0 * hp[o] + a1 * hp[64 + o];
    }
    for (int i = beg + 64; i < end; ++i) {  // rare: deg > 64
        int s = sperm[i];
        float2 esv = *reinterpret_cast<const float2*>(es + (size_t)s * 2);
        float a0 = __expf(lrelu_f(esv.x + edv.x) - m0) * r0;
        float a1 = __expf(lrelu_f(esv.y + edv.y) - m1) * r1;
        const float* hp = h1 + (size_t)s * 128;
        acc += a0 * hp[o] + a1 * hp[64 + o];
    }
    g1[(size_t)d * 64 + o] = acc;
}

// ---------------- aggregation layer2: one wave per dst node, 2 channels/lane ----------------
__global__ __launch_bounds__(256) void gat_agg2(
        const int* __restrict__ ofs, const int* __restrict__ sperm,
        const float* __restrict__ es, const float* __restrict__ ed,
        const float* __restrict__ h2, float* __restrict__ g2, int N) {
    int d = blockIdx.x * 4 + (threadIdx.x >> 6);
    if (d >= N) return;
    int lane = threadIdx.x & 63;
    int beg = ofs[d], end = ofs[d + 1];
    int deg = end - beg;
    float2 edv = *reinterpret_cast<const float2*>(ed + (size_t)d * 2);

    int s_f = 0;
    float e0f = neg_inf_f(), e1f = neg_inf_f();
    float m0 = neg_inf_f(), m1 = neg_inf_f();
    int i0 = beg + lane;
    if (i0 < end) {
        s_f = sperm[i0];
        float2 esv = *reinterpret_cast<const float2*>(es + (size_t)s_f * 2);
        e0f = lrelu_f(esv.x + edv.x);
        e1f = lrelu_f(esv.y + edv.y);
        m0 = e0f; m1 = e1f;
    }
    for (int i = i0 + 64; i < end; i += 64) {
        int s = sperm[i];
        float2 esv = *reinterpret_cast<const float2*>(es + (size_t)s * 2);
        m0 = fmaxf(m0, lrelu_f(esv.x + edv.x));
        m1 = fmaxf(m1, lrelu_f(esv.y + edv.y));
    }
    #pragma unroll
    for (int off = 32; off > 0; off >>= 1) {
        m0 = fmaxf(m0, __shfl_xor(m0, off, 64));
        m1 = fmaxf(m1, __shfl_xor(m1, off, 64));
    }
    float s0 = 0.f, s1 = 0.f;
    if (i0 < end) { s0 = __expf(e0f - m0); s1 = __expf(e1f - m1); }
    for (int i = i0 + 64; i < end; i += 64) {
        int s = sperm[i];
        float2 esv = *reinterpret_cast<const float2*>(es + (size_t)s * 2);
        s0 += __expf(lrelu_f(esv.x + edv.x) - m0);
        s1 += __expf(lrelu_f(esv.y + edv.y) - m1);
    }
    s0 = waveReduceSum(s0);
    s1 = waveReduceSum(s1);
    float r0 = 0.5f / (s0 + GAT_EPS), r1 = 0.5f / (s1 + GAT_EPS);
    float a0f = __expf(e0f - m0) * r0;
    float a1f = __expf(e1f - m1) * r1;

    float acc0 = 0.f, acc1 = 0.f;  // channels lane, lane+64
    int jmax = deg < 64 ? deg : 64;
    for (int j = 0; j < jmax; ++j) {
        int s = __shfl(s_f, j, 64);
        float a0 = __shfl(a0f, j, 64);
        float a1 = __shfl(a1f, j, 64);
        const float* hp = h2 + (size_t)s * 256;
        acc0 += a0 * hp[lane]      + a1 * hp[128 + lane];
        acc1 += a0 * hp[64 + lane] + a1 * hp[192 + lane];
    }
    for (int i = beg + 64; i < end; ++i) {
        int s = sperm[i];
        float2 esv = *reinterpret_cast<const float2*>(es + (size_t)s * 2);
        float a0 = __expf(lrelu_f(esv.x + edv.x) - m0) * r0;
        float a1 = __expf(lrelu_f(esv.y + edv.y) - m1) * r1;
        const float* hp = h2 + (size_t)s * 256;
        acc0 += a0 * hp[lane]      + a1 * hp[128 + lane];
        acc1 += a0 * hp[64 + lane] + a1 * hp[192 + lane];
    }
    g2[(size_t)d * 128 + lane] = acc0;
    g2[(size_t)d * 128 + 64 + lane] = acc1;
}

// ---------------- pool: sums[batch[n]] += elu(g2[n]+b2); cnts[batch[n]] += 1 ----------------
__global__ __launch_bounds__(256) void pool_kernel(
        const float* __restrict__ g2, const float* __restrict__ b2,
        const int* __restrict__ batch, float* __restrict__ sums,
        float* __restrict__ cnts, int N) {
    int idx = blockIdx.x * 256 + threadIdx.x;
    if (idx >= N * 128) return;
    int n = idx >> 7, c = idx & 127;
    int b = batch[n];
    float v = elu_f(g2[idx] + b2[c]);
    atomicAdd(&sums[(size_t)b * 128 + c], v);
    if (c == 0) atomicAdd(&cnts[b], 1.f);
}

// ---------------- final: out = (sums/cnt) @ lo_w + lo_b ----------------
__global__ void final_kernel(
        const float* __restrict__ sums, const float* __restrict__ cnts,
        const float* __restrict__ w, const float* __restrict__ b,
        float* __restrict__ out, int G) {
    int g = blockIdx.x;
    int k = threadIdx.x;
    if (k >= 24) return;
    float inv = 1.f / fmaxf(cnts[g], 1.f);
    float acc = b[k];
    #pragma unroll
    for (int c = 0; c < 128; ++c) acc = fmaf(sums[g * 128 + c] * inv, w[c * 24 + k], acc);
    out[g * 24 + k] = acc;
}

extern "C" void kernel_launch(void* const* d_in, const int* in_sizes, int n_in,
                              void* d_out, int out_size, void* d_ws, size_t ws_size,
                              hipStream_t stream) {
    const float* x      = (const float*)d_in[0];
    const int*   ei     = (const int*)d_in[1];
    const int*   batch  = (const int*)d_in[2];
    const float* fc0_w  = (const float*)d_in[3];
    const float* fc0_b  = (const float*)d_in[4];
    const float* W1     = (const float*)d_in[5];
    const float* a_src1 = (const float*)d_in[6];
    const float* a_dst1 = (const float*)d_in[7];
    const float* b1     = (const float*)d_in[8];
    const float* W2     = (const float*)d_in[9];
    const float* a_src2 = (const float*)d_in[10];
    const float* a_dst2 = (const float*)d_in[11];
    const float* b2     = (const float*)d_in[12];
    const float* lo_w   = (const float*)d_in[13];
    const float* lo_b   = (const float*)d_in[14];
    float* out = (float*)d_out;

    const int N = in_sizes[0] / 16;
    const int E = in_sizes[1] / 2;
    const int G = out_size / 24;
    const int* src = ei;
    const int* dst = ei + E;

    char* wsb = (char*)d_ws;
    size_t off = 0;
    auto allocf = [&](size_t n) { float* p = (float*)(wsb + off); off += ((n * 4 + 255) & ~(size_t)255); return p; };
    auto alloci = [&](size_t n) { int* p = (int*)(wsb + off); off += ((n * 4 + 255) & ~(size_t)255); return p; };
    float* h0    = allocf((size_t)N * 32);
    float* hbuf  = allocf((size_t)N * 256);   // h1 uses N*128; h2 uses N*256
    float* g1    = allocf((size_t)N * 64);
    float* g2    = allocf((size_t)N * 128);
    float* es    = allocf((size_t)N * 2);
    float* ed    = allocf((size_t)N * 2);
    float* sums  = allocf((size_t)G * 128);
    float* cnts  = allocf((size_t)G);
    int* deg     = alloci((size_t)N);
    int* ofs     = alloci((size_t)N + 1);
    int* cursor  = alloci((size_t)N);
    int* sperm   = alloci((size_t)E);
    (void)ws_size;

    // init + CSR build (shared by both layers)
    init_kernel<<<(N + 255) / 256, 256, 0, stream>>>(deg, sums, cnts, N, G);
    hist_kernel<<<(E + 255) / 256, 256, 0, stream>>>(dst, deg, E);
    scan_kernel<<<1, 1024, 0, stream>>>(deg, ofs, cursor, N);
    scatter_kernel<<<(E + 255) / 256, 256, 0, stream>>>(src, dst, cursor, sperm, E);

    // fc0
    fc0_kernel<<<(N + 7) / 8, 256, 0, stream>>>(x, fc0_w, fc0_b, h0, N);

    // ---- GAT layer 1 ----
    gat_transform1<<<(N + 7) / 8, 128, 0, stream>>>(h0, W1, a_src1, a_dst1, hbuf, es, ed, N);
    gat_agg1<<<(N + 3) / 4, 256, 0, stream>>>(ofs, sperm, es, ed, hbuf, g1, N);

    // ---- GAT layer 2 ----
    gat_transform2<<<(N + 7) / 8, 256, 0, stream>>>(g1, b1, W2, a_src2, a_dst2, hbuf, es, ed, N);
    gat_agg2<<<(N + 3) / 4, 256, 0, stream>>>(ofs, sperm, es, ed, hbuf, g2, N);

    // ---- pool + final linear ----
    pool_kernel<<<(N * 128 + 255) / 256, 256, 0, stream>>>(g2, b2, batch, sums, cnts, N);
    final_kernel<<<G, 32, 0, stream>>>(sums, cnts, lo_w, lo_b, out, G);
}

// Round 3
// 530.562 us; speedup vs baseline: 2.3201x; 1.3733x over previous
//
#include <hip/hip_runtime.h>
#include <math.h>

#define NEG_SLOPE 0.2f
#define GAT_EPS 1e-16f

__device__ __forceinline__ float elu_f(float x) { return x > 0.f ? x : expm1f(x); }
__device__ __forceinline__ float lrelu_f(float x) { return x > 0.f ? x : NEG_SLOPE * x; }
__device__ __forceinline__ float neg_inf_f() { return __int_as_float(0xFF800000); }

__device__ __forceinline__ float waveReduceSum(float v) {
    #pragma unroll
    for (int off = 32; off > 0; off >>= 1) v += __shfl_xor(v, off, 64);
    return v;
}

// ---------------- init: zero deg, sums, cnts ----------------
__global__ void init_kernel(int* deg, float* sums, float* cnts, int N, int G) {
    int i = blockIdx.x * 256 + threadIdx.x;
    if (i < N) deg[i] = 0;
    if (i < G * 128) sums[i] = 0.f;
    if (i < G) cnts[i] = 0.f;
}

// ---------------- CSR build ----------------
__global__ __launch_bounds__(256) void hist_kernel(const int* __restrict__ dst,
                                                   int* __restrict__ deg, int E) {
    int e = blockIdx.x * 256 + threadIdx.x;
    if (e < E) atomicAdd(&deg[dst[e]], 1);
}

// hierarchical scan A: per-block (256-wide) exclusive scan; ofs gets partial, bsum gets block total
__global__ __launch_bounds__(256) void scan_blocks_kernel(const int* __restrict__ deg,
        int* __restrict__ ofs, int* __restrict__ bsum, int N) {
    __shared__ int wtot[4];
    int tid = threadIdx.x, lane = tid & 63, wid = tid >> 6;
    int i = blockIdx.x * 256 + tid;
    int v = (i < N) ? deg[i] : 0;
    int incl = v;
    #pragma unroll
    for (int off = 1; off < 64; off <<= 1) {
        int t = __shfl_up(incl, off, 64);
        if (lane >= off) incl += t;
    }
    if (lane == 63) wtot[wid] = incl;
    __syncthreads();
    int woff = 0;
    #pragma unroll
    for (int w = 0; w < 4; ++w) if (w < wid) woff += wtot[w];
    int excl = incl - v + woff;
    if (i < N) ofs[i] = excl;
    if (tid == 255) bsum[blockIdx.x] = woff + incl;
}

// hierarchical scan B: single block scans nb (<=1024) block totals; writes total to ofs[N]
__global__ __launch_bounds__(1024) void scan_bsum_kernel(const int* __restrict__ bsum,
        int* __restrict__ bofs, int* __restrict__ ofsN, int nb) {
    __shared__ int wsum[16];
    int tid = threadIdx.x, lane = tid & 63, wid = tid >> 6;
    int v = (tid < nb) ? bsum[tid] : 0;
    int incl = v;
    #pragma unroll
    for (int off = 1; off < 64; off <<= 1) {
        int t = __shfl_up(incl, off, 64);
        if (lane >= off) incl += t;
    }
    if (lane == 63) wsum[wid] = incl;
    __syncthreads();
    if (wid == 0) {
        int wv = (lane < 16) ? wsum[lane] : 0;
        int winc = wv;
        #pragma unroll
        for (int off = 1; off < 16; off <<= 1) {
            int t = __shfl_up(winc, off, 64);
            if (lane >= off) winc += t;
        }
        if (lane < 16) wsum[lane] = winc - wv;  // exclusive wave offset
    }
    __syncthreads();
    int excl = incl - v + wsum[wid];
    if (tid < nb) bofs[tid] = excl;
    if (tid == nb - 1) *ofsN = excl + v;
}

// hierarchical scan C: add block offsets; fill cursor
__global__ __launch_bounds__(256) void scan_add_kernel(int* __restrict__ ofs,
        const int* __restrict__ bofs, int* __restrict__ cursor, int N) {
    int i = blockIdx.x * 256 + threadIdx.x;
    if (i < N) {
        int v = ofs[i] + bofs[blockIdx.x];
        ofs[i] = v;
        cursor[i] = v;
    }
}

__global__ __launch_bounds__(256) void scatter_kernel(
        const int* __restrict__ src, const int* __restrict__ dst,
        int* __restrict__ cursor, int* __restrict__ sperm, int E) {
    int e = blockIdx.x * 256 + threadIdx.x;
    if (e >= E) return;
    int d = dst[e];
    int pos = atomicAdd(&cursor[d], 1);
    sperm[pos] = src[e];
}

// ---------------- fc0: h0 = elu(x @ W + b), x[N,16], W[16,32] ----------------
__global__ __launch_bounds__(256) void fc0_kernel(
        const float* __restrict__ x, const float* __restrict__ w,
        const float* __restrict__ b, float* __restrict__ h0, int N) {
    __shared__ float xs[8 * 16];
    int n0 = blockIdx.x * 8;
    int tid = threadIdx.x;
    if (tid < 128) {
        int gi = n0 * 16 + tid;
        xs[tid] = (gi < N * 16) ? x[gi] : 0.f;
    }
    __syncthreads();
    int j = tid >> 5, o = tid & 31;
    int n = n0 + j;
    float acc = b[o];
    #pragma unroll
    for (int c = 0; c < 16; ++c) acc = fmaf(xs[j * 16 + c], w[c * 32 + o], acc);
    if (n < N) h0[n * 32 + o] = elu_f(acc);
}

// ---------------- GAT layer1 transform: h1[N,2,64] = h0 @ W1; e_src/e_dst ----------------
__global__ __launch_bounds__(128) void gat_transform1(
        const float* __restrict__ h0, const float* __restrict__ W,
        const float* __restrict__ asrc, const float* __restrict__ adst,
        float* __restrict__ h1, float* __restrict__ es, float* __restrict__ ed, int N) {
    __shared__ float xs[8 * 32];
    int n0 = blockIdx.x * 8;
    int tid = threadIdx.x;
    for (int idx = tid; idx < 8 * 32; idx += 128) {
        int gi = n0 * 32 + idx;
        xs[idx] = (gi < N * 32) ? h0[gi] : 0.f;
    }
    __syncthreads();
    int h = tid >> 6, lane = tid & 63, o = lane;
    float acc[8];
    #pragma unroll
    for (int j = 0; j < 8; ++j) acc[j] = 0.f;
    const float* wp = W + h * (32 * 64) + o;
    #pragma unroll
    for (int c = 0; c < 32; ++c) {
        float wv = wp[c * 64];
        #pragma unroll
        for (int j = 0; j < 8; ++j) acc[j] = fmaf(xs[j * 32 + c], wv, acc[j]);
    }
    float as = asrc[h * 64 + o], ad = adst[h * 64 + o];
    for (int j = 0; j < 8; ++j) {
        int n = n0 + j;
        if (n < N) h1[(size_t)n * 128 + tid] = acc[j];
        float vs = waveReduceSum(acc[j] * as);
        float vd = waveReduceSum(acc[j] * ad);
        if (lane == 0 && n < N) { es[n * 2 + h] = vs; ed[n * 2 + h] = vd; }
    }
}

// ---------------- GAT layer2 transform: h2[N,2,128] = elu(g1+b1) @ W2 ----------------
__global__ __launch_bounds__(256) void gat_transform2(
        const float* __restrict__ g1, const float* __restrict__ b1,
        const float* __restrict__ W, const float* __restrict__ asrc,
        const float* __restrict__ adst, float* __restrict__ h2,
        float* __restrict__ es, float* __restrict__ ed, int N) {
    __shared__ float xs[8 * 64];
    __shared__ float esl[16], edl[16];
    int n0 = blockIdx.x * 8;
    int tid = threadIdx.x;
    for (int idx = tid; idx < 8 * 64; idx += 256) {
        int gi = n0 * 64 + idx;
        float v = (gi < N * 64) ? g1[gi] : 0.f;
        xs[idx] = elu_f(v + b1[idx & 63]);
    }
    if (tid < 16) { esl[tid] = 0.f; edl[tid] = 0.f; }
    __syncthreads();
    int h = tid >> 7, o = tid & 127, lane = tid & 63;
    float acc[8];
    #pragma unroll
    for (int j = 0; j < 8; ++j) acc[j] = 0.f;
    const float* wp = W + h * (64 * 128) + o;
    for (int c = 0; c < 64; ++c) {
        float wv = wp[c * 128];
        #pragma unroll
        for (int j = 0; j < 8; ++j) acc[j] = fmaf(xs[j * 64 + c], wv, acc[j]);
    }
    float as = asrc[h * 128 + o], ad = adst[h * 128 + o];
    #pragma unroll
    for (int j = 0; j < 8; ++j) {
        int n = n0 + j;
        if (n < N) h2[(size_t)n * 256 + tid] = acc[j];
        float vs = waveReduceSum(acc[j] * as);
        float vd = waveReduceSum(acc[j] * ad);
        if (lane == 0) { atomicAdd(&esl[j * 2 + h], vs); atomicAdd(&edl[j * 2 + h], vd); }
    }
    __syncthreads();
    if (tid < 16) {
        int j = tid >> 1, hh = tid & 1, n = n0 + j;
        if (n < N) { es[n * 2 + hh] = esl[tid]; ed[n * 2 + hh] = edl[tid]; }
    }
}

// ---------------- aggregation layer1: one wave per dst node ----------------
__global__ __launch_bounds__(256) void gat_agg1(
        const int* __restrict__ ofs, const int* __restrict__ sperm,
        const float* __restrict__ es, const float* __restrict__ ed,
        const float* __restrict__ h1, float* __restrict__ g1, int N) {
    int d = blockIdx.x * 4 + (threadIdx.x >> 6);
    if (d >= N) return;
    int lane = threadIdx.x & 63;
    int beg = ofs[d], end = ofs[d + 1];
    int deg = end - beg;
    float2 edv = *reinterpret_cast<const float2*>(ed + (size_t)d * 2);

    int s_f = 0;
    float e0f = neg_inf_f(), e1f = neg_inf_f();
    float m0 = neg_inf_f(), m1 = neg_inf_f();
    int i0 = beg + lane;
    if (i0 < end) {
        s_f = sperm[i0];
        float2 esv = *reinterpret_cast<const float2*>(es + (size_t)s_f * 2);
        e0f = lrelu_f(esv.x + edv.x);
        e1f = lrelu_f(esv.y + edv.y);
        m0 = e0f; m1 = e1f;
    }
    for (int i = i0 + 64; i < end; i += 64) {
        int s = sperm[i];
        float2 esv = *reinterpret_cast<const float2*>(es + (size_t)s * 2);
        m0 = fmaxf(m0, lrelu_f(esv.x + edv.x));
        m1 = fmaxf(m1, lrelu_f(esv.y + edv.y));
    }
    #pragma unroll
    for (int off = 32; off > 0; off >>= 1) {
        m0 = fmaxf(m0, __shfl_xor(m0, off, 64));
        m1 = fmaxf(m1, __shfl_xor(m1, off, 64));
    }
    float s0 = 0.f, s1 = 0.f;
    if (i0 < end) { s0 = __expf(e0f - m0); s1 = __expf(e1f - m1); }
    for (int i = i0 + 64; i < end; i += 64) {
        int s = sperm[i];
        float2 esv = *reinterpret_cast<const float2*>(es + (size_t)s * 2);
        s0 += __expf(lrelu_f(esv.x + edv.x) - m0);
        s1 += __expf(lrelu_f(esv.y + edv.y) - m1);
    }
    s0 = waveReduceSum(s0);
    s1 = waveReduceSum(s1);
    float r0 = 0.5f / (s0 + GAT_EPS), r1 = 0.5f / (s1 + GAT_EPS);
    float a0f = __expf(e0f - m0) * r0;
    float a1f = __expf(e1f - m1) * r1;

    float acc = 0.f;
    int o = lane;
    int jmax = deg < 64 ? deg : 64;
    for (int j = 0; j < jmax; ++j) {
        int s = __shfl(s_f, j, 64);
        float a0 = __shfl(a0f, j, 64);
        float a1 = __shfl(a1f, j, 64);
        const float* hp = h1 + (size_t)s * 128;
        acc += a0 * hp[o] + a1 * hp[64 + o];
    }
    for (int i = beg + 64; i < end; ++i) {
        int s = sperm[i];
        float2 esv = *reinterpret_cast<const float2*>(es + (size_t)s * 2);
        float a0 = __expf(lrelu_f(esv.x + edv.x) - m0) * r0;
        float a1 = __expf(lrelu_f(esv.y + edv.y) - m1) * r1;
        const float* hp = h1 + (size_t)s * 128;
        acc += a0 * hp[o] + a1 * hp[64 + o];
    }
    g1[(size_t)d * 64 + o] = acc;
}

// ---------------- aggregation layer2: one wave per dst node, 2 channels/lane ----------------
__global__ __launch_bounds__(256) void gat_agg2(
        const int* __restrict__ ofs, const int* __restrict__ sperm,
        const float* __restrict__ es, const float* __restrict__ ed,
        const float* __restrict__ h2, float* __restrict__ g2, int N) {
    int d = blockIdx.x * 4 + (threadIdx.x >> 6);
    if (d >= N) return;
    int lane = threadIdx.x & 63;
    int beg = ofs[d], end = ofs[d + 1];
    int deg = end - beg;
    float2 edv = *reinterpret_cast<const float2*>(ed + (size_t)d * 2);

    int s_f = 0;
    float e0f = neg_inf_f(), e1f = neg_inf_f();
    float m0 = neg_inf_f(), m1 = neg_inf_f();
    int i0 = beg + lane;
    if (i0 < end) {
        s_f = sperm[i0];
        float2 esv = *reinterpret_cast<const float2*>(es + (size_t)s_f * 2);
        e0f = lrelu_f(esv.x + edv.x);
        e1f = lrelu_f(esv.y + edv.y);
        m0 = e0f; m1 = e1f;
    }
    for (int i = i0 + 64; i < end; i += 64) {
        int s = sperm[i];
        float2 esv = *reinterpret_cast<const float2*>(es + (size_t)s * 2);
        m0 = fmaxf(m0, lrelu_f(esv.x + edv.x));
        m1 = fmaxf(m1, lrelu_f(esv.y + edv.y));
    }
    #pragma unroll
    for (int off = 32; off > 0; off >>= 1) {
        m0 = fmaxf(m0, __shfl_xor(m0, off, 64));
        m1 = fmaxf(m1, __shfl_xor(m1, off, 64));
    }
    float s0 = 0.f, s1 = 0.f;
    if (i0 < end) { s0 = __expf(e0f - m0); s1 = __expf(e1f - m1); }
    for (int i = i0 + 64; i < end; i += 64) {
        int s = sperm[i];
        float2 esv = *reinterpret_cast<const float2*>(es + (size_t)s * 2);
        s0 += __expf(lrelu_f(esv.x + edv.x) - m0);
        s1 += __expf(lrelu_f(esv.y + edv.y) - m1);
    }
    s0 = waveReduceSum(s0);
    s1 = waveReduceSum(s1);
    float r0 = 0.5f / (s0 + GAT_EPS), r1 = 0.5f / (s1 + GAT_EPS);
    float a0f = __expf(e0f - m0) * r0;
    float a1f = __expf(e1f - m1) * r1;

    float acc0 = 0.f, acc1 = 0.f;
    int jmax = deg < 64 ? deg : 64;
    for (int j = 0; j < jmax; ++j) {
        int s = __shfl(s_f, j, 64);
        float a0 = __shfl(a0f, j, 64);
        float a1 = __shfl(a1f, j, 64);
        const float* hp = h2 + (size_t)s * 256;
        acc0 += a0 * hp[lane]      + a1 * hp[128 + lane];
        acc1 += a0 * hp[64 + lane] + a1 * hp[192 + lane];
    }
    for (int i = beg + 64; i < end; ++i) {
        int s = sperm[i];
        float2 esv = *reinterpret_cast<const float2*>(es + (size_t)s * 2);
        float a0 = __expf(lrelu_f(esv.x + edv.x) - m0) * r0;
        float a1 = __expf(lrelu_f(esv.y + edv.y) - m1) * r1;
        const float* hp = h2 + (size_t)s * 256;
        acc0 += a0 * hp[lane]      + a1 * hp[128 + lane];
        acc1 += a0 * hp[64 + lane] + a1 * hp[192 + lane];
    }
    g2[(size_t)d * 128 + lane] = acc0;
    g2[(size_t)d * 128 + 64 + lane] = acc1;
}

// ---------------- pool: sorted-batch run accumulation ----------------
// block = 256 threads = 2 node-streams x 128 channels; POOL_NPB consecutive nodes/block
#define POOL_NPB 128
__global__ __launch_bounds__(256) void pool_kernel(
        const float* __restrict__ g2, const float* __restrict__ b2,
        const int* __restrict__ batch, float* __restrict__ sums,
        float* __restrict__ cnts, int N) {
    int n0 = blockIdx.x * POOL_NPB;
    int c = threadIdx.x & 127;
    int p = threadIdx.x >> 7;          // node-stream 0/1, stride 2
    int nend = n0 + POOL_NPB; if (nend > N) nend = N;
    int n = n0 + p;
    if (n >= nend) return;
    float bc = b2[c];
    int cur_b = batch[n];
    float acc = 0.f;
    int cnt = 0;
    for (; n < nend; n += 2) {
        int b = batch[n];                       // wave-uniform
        if (b != cur_b) {
            atomicAdd(&sums[(size_t)cur_b * 128 + c], acc);
            if (c == 0) atomicAdd(&cnts[cur_b], (float)cnt);
            acc = 0.f; cnt = 0; cur_b = b;
        }
        acc += elu_f(g2[(size_t)n * 128 + c] + bc);
        ++cnt;
    }
    atomicAdd(&sums[(size_t)cur_b * 128 + c], acc);
    if (c == 0) atomicAdd(&cnts[cur_b], (float)cnt);
}

// ---------------- final: out = (sums/cnt) @ lo_w + lo_b ----------------
__global__ void final_kernel(
        const float* __restrict__ sums, const float* __restrict__ cnts,
        const float* __restrict__ w, const float* __restrict__ b,
        float* __restrict__ out, int G) {
    int g = blockIdx.x;
    int k = threadIdx.x;
    if (k >= 24) return;
    float inv = 1.f / fmaxf(cnts[g], 1.f);
    float acc = b[k];
    #pragma unroll
    for (int c = 0; c < 128; ++c) acc = fmaf(sums[g * 128 + c] * inv, w[c * 24 + k], acc);
    out[g * 24 + k] = acc;
}

extern "C" void kernel_launch(void* const* d_in, const int* in_sizes, int n_in,
                              void* d_out, int out_size, void* d_ws, size_t ws_size,
                              hipStream_t stream) {
    const float* x      = (const float*)d_in[0];
    const int*   ei     = (const int*)d_in[1];
    const int*   batch  = (const int*)d_in[2];
    const float* fc0_w  = (const float*)d_in[3];
    const float* fc0_b  = (const float*)d_in[4];
    const float* W1     = (const float*)d_in[5];
    const float* a_src1 = (const float*)d_in[6];
    const float* a_dst1 = (const float*)d_in[7];
    const float* b1     = (const float*)d_in[8];
    const float* W2     = (const float*)d_in[9];
    const float* a_src2 = (const float*)d_in[10];
    const float* a_dst2 = (const float*)d_in[11];
    const float* b2     = (const float*)d_in[12];
    const float* lo_w   = (const float*)d_in[13];
    const float* lo_b   = (const float*)d_in[14];
    float* out = (float*)d_out;

    const int N = in_sizes[0] / 16;
    const int E = in_sizes[1] / 2;
    const int G = out_size / 24;
    const int* src = ei;
    const int* dst = ei + E;
    const int nb = (N + 255) / 256;   // <= 1024 supported by scan_bsum_kernel

    char* wsb = (char*)d_ws;
    size_t off = 0;
    auto allocf = [&](size_t n) { float* p = (float*)(wsb + off); off += ((n * 4 + 255) & ~(size_t)255); return p; };
    auto alloci = [&](size_t n) { int* p = (int*)(wsb + off); off += ((n * 4 + 255) & ~(size_t)255); return p; };
    float* h0    = allocf((size_t)N * 32);
    float* hbuf  = allocf((size_t)N * 256);   // h1 uses N*128; h2 uses N*256
    float* g1    = allocf((size_t)N * 64);
    float* g2    = allocf((size_t)N * 128);
    float* es    = allocf((size_t)N * 2);
    float* ed    = allocf((size_t)N * 2);
    float* sums  = allocf((size_t)G * 128);
    float* cnts  = allocf((size_t)G);
    int* deg     = alloci((size_t)N);
    int* ofs     = alloci((size_t)N + 1);
    int* cursor  = alloci((size_t)N);
    int* sperm   = alloci((size_t)E);
    int* bsum    = alloci((size_t)nb);
    int* bofs    = alloci((size_t)nb);
    (void)ws_size;

    // init + CSR build (shared by both layers)
    init_kernel<<<(N + 255) / 256, 256, 0, stream>>>(deg, sums, cnts, N, G);
    hist_kernel<<<(E + 255) / 256, 256, 0, stream>>>(dst, deg, E);
    scan_blocks_kernel<<<nb, 256, 0, stream>>>(deg, ofs, bsum, N);
    scan_bsum_kernel<<<1, 1024, 0, stream>>>(bsum, bofs, ofs + N, nb);
    scan_add_kernel<<<nb, 256, 0, stream>>>(ofs, bofs, cursor, N);
    scatter_kernel<<<(E + 255) / 256, 256, 0, stream>>>(src, dst, cursor, sperm, E);

    // fc0
    fc0_kernel<<<(N + 7) / 8, 256, 0, stream>>>(x, fc0_w, fc0_b, h0, N);

    // ---- GAT layer 1 ----
    gat_transform1<<<(N + 7) / 8, 128, 0, stream>>>(h0, W1, a_src1, a_dst1, hbuf, es, ed, N);
    gat_agg1<<<(N + 3) / 4, 256, 0, stream>>>(ofs, sperm, es, ed, hbuf, g1, N);

    // ---- GAT layer 2 ----
    gat_transform2<<<(N + 7) / 8, 256, 0, stream>>>(g1, b1, W2, a_src2, a_dst2, hbuf, es, ed, N);
    gat_agg2<<<(N + 3) / 4, 256, 0, stream>>>(ofs, sperm, es, ed, hbuf, g2, N);

    // ---- pool + final linear ----
    pool_kernel<<<(N + POOL_NPB - 1) / POOL_NPB, 256, 0, stream>>>(g2, b2, batch, sums, cnts, N);
    final_kernel<<<G, 32, 0, stream>>>(sums, cnts, lo_w, lo_b, out, G);
}

// Round 4
// 472.408 us; speedup vs baseline: 2.6057x; 1.1231x over previous
//
#include <hip/hip_runtime.h>
#include <hip/hip_fp16.h>
#include <math.h>

#define NEG_SLOPE 0.2f
#define GAT_EPS 1e-16f

__device__ __forceinline__ float elu_f(float x) { return x > 0.f ? x : expm1f(x); }
__device__ __forceinline__ float lrelu_f(float x) { return x > 0.f ? x : NEG_SLOPE * x; }
__device__ __forceinline__ float neg_inf_f() { return __int_as_float(0xFF800000); }

__device__ __forceinline__ float waveReduceSum(float v) {
    #pragma unroll
    for (int off = 32; off > 0; off >>= 1) v += __shfl_xor(v, off, 64);
    return v;
}

// ---------------- init: zero deg, sums, cnts ----------------
__global__ void init_kernel(int* deg, float* sums, float* cnts, int N, int G) {
    int i = blockIdx.x * 256 + threadIdx.x;
    if (i < N) deg[i] = 0;
    if (i < G * 128) sums[i] = 0.f;
    if (i < G) cnts[i] = 0.f;
}

// ---------------- CSR build ----------------
__global__ __launch_bounds__(256) void hist_kernel(const int* __restrict__ dst,
                                                   int* __restrict__ deg, int E) {
    int e = blockIdx.x * 256 + threadIdx.x;
    if (e < E) atomicAdd(&deg[dst[e]], 1);
}

__global__ __launch_bounds__(256) void scan_blocks_kernel(const int* __restrict__ deg,
        int* __restrict__ ofs, int* __restrict__ bsum, int N) {
    __shared__ int wtot[4];
    int tid = threadIdx.x, lane = tid & 63, wid = tid >> 6;
    int i = blockIdx.x * 256 + tid;
    int v = (i < N) ? deg[i] : 0;
    int incl = v;
    #pragma unroll
    for (int off = 1; off < 64; off <<= 1) {
        int t = __shfl_up(incl, off, 64);
        if (lane >= off) incl += t;
    }
    if (lane == 63) wtot[wid] = incl;
    __syncthreads();
    int woff = 0;
    #pragma unroll
    for (int w = 0; w < 4; ++w) if (w < wid) woff += wtot[w];
    int excl = incl - v + woff;
    if (i < N) ofs[i] = excl;
    if (tid == 255) bsum[blockIdx.x] = woff + incl;
}

__global__ __launch_bounds__(1024) void scan_bsum_kernel(const int* __restrict__ bsum,
        int* __restrict__ bofs, int* __restrict__ ofsN, int nb) {
    __shared__ int wsum[16];
    int tid = threadIdx.x, lane = tid & 63, wid = tid >> 6;
    int v = (tid < nb) ? bsum[tid] : 0;
    int incl = v;
    #pragma unroll
    for (int off = 1; off < 64; off <<= 1) {
        int t = __shfl_up(incl, off, 64);
        if (lane >= off) incl += t;
    }
    if (lane == 63) wsum[wid] = incl;
    __syncthreads();
    if (wid == 0) {
        int wv = (lane < 16) ? wsum[lane] : 0;
        int winc = wv;
        #pragma unroll
        for (int off = 1; off < 16; off <<= 1) {
            int t = __shfl_up(winc, off, 64);
            if (lane >= off) winc += t;
        }
        if (lane < 16) wsum[lane] = winc - wv;
    }
    __syncthreads();
    int excl = incl - v + wsum[wid];
    if (tid < nb) bofs[tid] = excl;
    if (tid == nb - 1) *ofsN = excl + v;
}

__global__ __launch_bounds__(256) void scan_add_kernel(int* __restrict__ ofs,
        const int* __restrict__ bofs, int* __restrict__ cursor, int N) {
    int i = blockIdx.x * 256 + threadIdx.x;
    if (i < N) {
        int v = ofs[i] + bofs[blockIdx.x];
        ofs[i] = v;
        cursor[i] = v;
    }
}

__global__ __launch_bounds__(256) void scatter_kernel(
        const int* __restrict__ src, const int* __restrict__ dst,
        int* __restrict__ cursor, int* __restrict__ sperm, int E) {
    int e = blockIdx.x * 256 + threadIdx.x;
    if (e >= E) return;
    int d = dst[e];
    int pos = atomicAdd(&cursor[d], 1);
    sperm[pos] = src[e];
}

// ---------------- fc0: h0 = elu(x @ W + b), x[N,16], W[16,32] ----------------
__global__ __launch_bounds__(256) void fc0_kernel(
        const float* __restrict__ x, const float* __restrict__ w,
        const float* __restrict__ b, float* __restrict__ h0, int N) {
    __shared__ float xs[8 * 16];
    int n0 = blockIdx.x * 8;
    int tid = threadIdx.x;
    if (tid < 128) {
        int gi = n0 * 16 + tid;
        xs[tid] = (gi < N * 16) ? x[gi] : 0.f;
    }
    __syncthreads();
    int j = tid >> 5, o = tid & 31;
    int n = n0 + j;
    float acc = b[o];
    #pragma unroll
    for (int c = 0; c < 16; ++c) acc = fmaf(xs[j * 16 + c], w[c * 32 + o], acc);
    if (n < N) h0[n * 32 + o] = elu_f(acc);
}

// ---------------- GAT layer1 transform ----------------
// h1 written fp16 packed: half index n*128 + 2*o + h  (half2 .x=head0,.y=head1 per channel o)
__global__ __launch_bounds__(128) void gat_transform1(
        const float* __restrict__ h0, const float* __restrict__ W,
        const float* __restrict__ asrc, const float* __restrict__ adst,
        __half* __restrict__ h1, float* __restrict__ es, float* __restrict__ ed, int N) {
    __shared__ float xs[8 * 32];
    int n0 = blockIdx.x * 8;
    int tid = threadIdx.x;
    for (int idx = tid; idx < 8 * 32; idx += 128) {
        int gi = n0 * 32 + idx;
        xs[idx] = (gi < N * 32) ? h0[gi] : 0.f;
    }
    __syncthreads();
    int h = tid >> 6, lane = tid & 63, o = lane;
    float acc[8];
    #pragma unroll
    for (int j = 0; j < 8; ++j) acc[j] = 0.f;
    const float* wp = W + h * (32 * 64) + o;
    #pragma unroll
    for (int c = 0; c < 32; ++c) {
        float wv = wp[c * 64];
        #pragma unroll
        for (int j = 0; j < 8; ++j) acc[j] = fmaf(xs[j * 32 + c], wv, acc[j]);
    }
    float as = asrc[h * 64 + o], ad = adst[h * 64 + o];
    for (int j = 0; j < 8; ++j) {
        int n = n0 + j;
        if (n < N) h1[(size_t)n * 128 + 2 * o + h] = __float2half(acc[j]);
        float vs = waveReduceSum(acc[j] * as);
        float vd = waveReduceSum(acc[j] * ad);
        if (lane == 0 && n < N) { es[n * 2 + h] = vs; ed[n * 2 + h] = vd; }
    }
}

// ---------------- GAT layer2 transform ----------------
// h2 written fp16 packed: half index n*256 + 2*o + h  (o in [0,128))
__global__ __launch_bounds__(256) void gat_transform2(
        const float* __restrict__ g1, const float* __restrict__ b1,
        const float* __restrict__ W, const float* __restrict__ asrc,
        const float* __restrict__ adst, __half* __restrict__ h2,
        float* __restrict__ es, float* __restrict__ ed, int N) {
    __shared__ float xs[8 * 64];
    __shared__ float esl[16], edl[16];
    int n0 = blockIdx.x * 8;
    int tid = threadIdx.x;
    for (int idx = tid; idx < 8 * 64; idx += 256) {
        int gi = n0 * 64 + idx;
        float v = (gi < N * 64) ? g1[gi] : 0.f;
        xs[idx] = elu_f(v + b1[idx & 63]);
    }
    if (tid < 16) { esl[tid] = 0.f; edl[tid] = 0.f; }
    __syncthreads();
    int h = tid >> 7, o = tid & 127, lane = tid & 63;
    float acc[8];
    #pragma unroll
    for (int j = 0; j < 8; ++j) acc[j] = 0.f;
    const float* wp = W + h * (64 * 128) + o;
    for (int c = 0; c < 64; ++c) {
        float wv = wp[c * 128];
        #pragma unroll
        for (int j = 0; j < 8; ++j) acc[j] = fmaf(xs[j * 64 + c], wv, acc[j]);
    }
    float as = asrc[h * 128 + o], ad = adst[h * 128 + o];
    #pragma unroll
    for (int j = 0; j < 8; ++j) {
        int n = n0 + j;
        if (n < N) h2[(size_t)n * 256 + 2 * o + h] = __float2half(acc[j]);
        float vs = waveReduceSum(acc[j] * as);
        float vd = waveReduceSum(acc[j] * ad);
        if (lane == 0) { atomicAdd(&esl[j * 2 + h], vs); atomicAdd(&edl[j * 2 + h], vd); }
    }
    __syncthreads();
    if (tid < 16) {
        int j = tid >> 1, hh = tid & 1, n = n0 + j;
        if (n < N) { es[n * 2 + hh] = esl[tid]; ed[n * 2 + hh] = edl[tid]; }
    }
}

// ---------------- aggregation layer1: one wave per dst node ----------------
__global__ __launch_bounds__(256) void gat_agg1(
        const int* __restrict__ ofs, const int* __restrict__ sperm,
        const float* __restrict__ es, const float* __restrict__ ed,
        const __half2* __restrict__ h1, float* __restrict__ g1, int N) {
    int d = blockIdx.x * 4 + (threadIdx.x >> 6);
    if (d >= N) return;
    int lane = threadIdx.x & 63;
    int beg = ofs[d], end = ofs[d + 1];
    int deg = end - beg;
    float2 edv = *reinterpret_cast<const float2*>(ed + (size_t)d * 2);

    int s_f = 0;
    float e0f = neg_inf_f(), e1f = neg_inf_f();
    float m0 = neg_inf_f(), m1 = neg_inf_f();
    int i0 = beg + lane;
    if (i0 < end) {
        s_f = sperm[i0];
        float2 esv = *reinterpret_cast<const float2*>(es + (size_t)s_f * 2);
        e0f = lrelu_f(esv.x + edv.x);
        e1f = lrelu_f(esv.y + edv.y);
        m0 = e0f; m1 = e1f;
    }
    for (int i = i0 + 64; i < end; i += 64) {
        int s = sperm[i];
        float2 esv = *reinterpret_cast<const float2*>(es + (size_t)s * 2);
        m0 = fmaxf(m0, lrelu_f(esv.x + edv.x));
        m1 = fmaxf(m1, lrelu_f(esv.y + edv.y));
    }
    #pragma unroll
    for (int off = 32; off > 0; off >>= 1) {
        m0 = fmaxf(m0, __shfl_xor(m0, off, 64));
        m1 = fmaxf(m1, __shfl_xor(m1, off, 64));
    }
    float s0 = 0.f, s1 = 0.f;
    if (i0 < end) { s0 = __expf(e0f - m0); s1 = __expf(e1f - m1); }
    for (int i = i0 + 64; i < end; i += 64) {
        int s = sperm[i];
        float2 esv = *reinterpret_cast<const float2*>(es + (size_t)s * 2);
        s0 += __expf(lrelu_f(esv.x + edv.x) - m0);
        s1 += __expf(lrelu_f(esv.y + edv.y) - m1);
    }
    s0 = waveReduceSum(s0);
    s1 = waveReduceSum(s1);
    float r0 = 0.5f / (s0 + GAT_EPS), r1 = 0.5f / (s1 + GAT_EPS);
    float a0f = __expf(e0f - m0) * r0;
    float a1f = __expf(e1f - m1) * r1;

    float acc = 0.f;
    int jmax = deg < 64 ? deg : 64;
    for (int j = 0; j < jmax; ++j) {
        int s = __shfl(s_f, j, 64);
        float a0 = __shfl(a0f, j, 64);
        float a1 = __shfl(a1f, j, 64);
        float2 v = __half22float2(h1[(size_t)s * 64 + lane]);
        acc += a0 * v.x + a1 * v.y;
    }
    for (int i = beg + 64; i < end; ++i) {
        int s = sperm[i];
        float2 esv = *reinterpret_cast<const float2*>(es + (size_t)s * 2);
        float a0 = __expf(lrelu_f(esv.x + edv.x) - m0) * r0;
        float a1 = __expf(lrelu_f(esv.y + edv.y) - m1) * r1;
        float2 v = __half22float2(h1[(size_t)s * 64 + lane]);
        acc += a0 * v.x + a1 * v.y;
    }
    g1[(size_t)d * 64 + lane] = acc;
}

// ---------------- aggregation layer2: one wave per dst node, 2 channels/lane ----------------
__global__ __launch_bounds__(256) void gat_agg2(
        const int* __restrict__ ofs, const int* __restrict__ sperm,
        const float* __restrict__ es, const float* __restrict__ ed,
        const __half2* __restrict__ h2, float* __restrict__ g2, int N) {
    int d = blockIdx.x * 4 + (threadIdx.x >> 6);
    if (d >= N) return;
    int lane = threadIdx.x & 63;
    int beg = ofs[d], end = ofs[d + 1];
    int deg = end - beg;
    float2 edv = *reinterpret_cast<const float2*>(ed + (size_t)d * 2);

    int s_f = 0;
    float e0f = neg_inf_f(), e1f = neg_inf_f();
    float m0 = neg_inf_f(), m1 = neg_inf_f();
    int i0 = beg + lane;
    if (i0 < end) {
        s_f = sperm[i0];
        float2 esv = *reinterpret_cast<const float2*>(es + (size_t)s_f * 2);
        e0f = lrelu_f(esv.x + edv.x);
        e1f = lrelu_f(esv.y + edv.y);
        m0 = e0f; m1 = e1f;
    }
    for (int i = i0 + 64; i < end; i += 64) {
        int s = sperm[i];
        float2 esv = *reinterpret_cast<const float2*>(es + (size_t)s * 2);
        m0 = fmaxf(m0, lrelu_f(esv.x + edv.x));
        m1 = fmaxf(m1, lrelu_f(esv.y + edv.y));
    }
    #pragma unroll
    for (int off = 32; off > 0; off >>= 1) {
        m0 = fmaxf(m0, __shfl_xor(m0, off, 64));
        m1 = fmaxf(m1, __shfl_xor(m1, off, 64));
    }
    float s0 = 0.f, s1 = 0.f;
    if (i0 < end) { s0 = __expf(e0f - m0); s1 = __expf(e1f - m1); }
    for (int i = i0 + 64; i < end; i += 64) {
        int s = sperm[i];
        float2 esv = *reinterpret_cast<const float2*>(es + (size_t)s * 2);
        s0 += __expf(lrelu_f(esv.x + edv.x) - m0);
        s1 += __expf(lrelu_f(esv.y + edv.y) - m1);
    }
    s0 = waveReduceSum(s0);
    s1 = waveReduceSum(s1);
    float r0 = 0.5f / (s0 + GAT_EPS), r1 = 0.5f / (s1 + GAT_EPS);
    float a0f = __expf(e0f - m0) * r0;
    float a1f = __expf(e1f - m1) * r1;

    float acc0 = 0.f, acc1 = 0.f;  // channels lane, lane+64
    int jmax = deg < 64 ? deg : 64;
    for (int j = 0; j < jmax; ++j) {
        int s = __shfl(s_f, j, 64);
        float a0 = __shfl(a0f, j, 64);
        float a1 = __shfl(a1f, j, 64);
        const __half2* hp = h2 + (size_t)s * 128;
        float2 v0 = __half22float2(hp[lane]);
        float2 v1 = __half22float2(hp[64 + lane]);
        acc0 += a0 * v0.x + a1 * v0.y;
        acc1 += a0 * v1.x + a1 * v1.y;
    }
    for (int i = beg + 64; i < end; ++i) {
        int s = sperm[i];
        float2 esv = *reinterpret_cast<const float2*>(es + (size_t)s * 2);
        float a0 = __expf(lrelu_f(esv.x + edv.x) - m0) * r0;
        float a1 = __expf(lrelu_f(esv.y + edv.y) - m1) * r1;
        const __half2* hp = h2 + (size_t)s * 128;
        float2 v0 = __half22float2(hp[lane]);
        float2 v1 = __half22float2(hp[64 + lane]);
        acc0 += a0 * v0.x + a1 * v0.y;
        acc1 += a0 * v1.x + a1 * v1.y;
    }
    g2[(size_t)d * 128 + lane] = acc0;
    g2[(size_t)d * 128 + 64 + lane] = acc1;
}

// ---------------- pool: sorted-batch run accumulation ----------------
#define POOL_NPB 128
__global__ __launch_bounds__(256) void pool_kernel(
        const float* __restrict__ g2, const float* __restrict__ b2,
        const int* __restrict__ batch, float* __restrict__ sums,
        float* __restrict__ cnts, int N) {
    int n0 = blockIdx.x * POOL_NPB;
    int c = threadIdx.x & 127;
    int p = threadIdx.x >> 7;
    int nend = n0 + POOL_NPB; if (nend > N) nend = N;
    int n = n0 + p;
    if (n >= nend) return;
    float bc = b2[c];
    int cur_b = batch[n];
    float acc = 0.f;
    int cnt = 0;
    for (; n < nend; n += 2) {
        int b = batch[n];
        if (b != cur_b) {
            atomicAdd(&sums[(size_t)cur_b * 128 + c], acc);
            if (c == 0) atomicAdd(&cnts[cur_b], (float)cnt);
            acc = 0.f; cnt = 0; cur_b = b;
        }
        acc += elu_f(g2[(size_t)n * 128 + c] + bc);
        ++cnt;
    }
    atomicAdd(&sums[(size_t)cur_b * 128 + c], acc);
    if (c == 0) atomicAdd(&cnts[cur_b], (float)cnt);
}

// ---------------- final: out = (sums/cnt) @ lo_w + lo_b ----------------
__global__ void final_kernel(
        const float* __restrict__ sums, const float* __restrict__ cnts,
        const float* __restrict__ w, const float* __restrict__ b,
        float* __restrict__ out, int G) {
    int g = blockIdx.x;
    int k = threadIdx.x;
    if (k >= 24) return;
    float inv = 1.f / fmaxf(cnts[g], 1.f);
    float acc = b[k];
    #pragma unroll
    for (int c = 0; c < 128; ++c) acc = fmaf(sums[g * 128 + c] * inv, w[c * 24 + k], acc);
    out[g * 24 + k] = acc;
}

extern "C" void kernel_launch(void* const* d_in, const int* in_sizes, int n_in,
                              void* d_out, int out_size, void* d_ws, size_t ws_size,
                              hipStream_t stream) {
    const float* x      = (const float*)d_in[0];
    const int*   ei     = (const int*)d_in[1];
    const int*   batch  = (const int*)d_in[2];
    const float* fc0_w  = (const float*)d_in[3];
    const float* fc0_b  = (const float*)d_in[4];
    const float* W1     = (const float*)d_in[5];
    const float* a_src1 = (const float*)d_in[6];
    const float* a_dst1 = (const float*)d_in[7];
    const float* b1     = (const float*)d_in[8];
    const float* W2     = (const float*)d_in[9];
    const float* a_src2 = (const float*)d_in[10];
    const float* a_dst2 = (const float*)d_in[11];
    const float* b2     = (const float*)d_in[12];
    const float* lo_w   = (const float*)d_in[13];
    const float* lo_b   = (const float*)d_in[14];
    float* out = (float*)d_out;

    const int N = in_sizes[0] / 16;
    const int E = in_sizes[1] / 2;
    const int G = out_size / 24;
    const int* src = ei;
    const int* dst = ei + E;
    const int nb = (N + 255) / 256;

    char* wsb = (char*)d_ws;
    size_t off = 0;
    auto allocf = [&](size_t n) { float* p = (float*)(wsb + off); off += ((n * 4 + 255) & ~(size_t)255); return p; };
    auto alloci = [&](size_t n) { int* p = (int*)(wsb + off); off += ((n * 4 + 255) & ~(size_t)255); return p; };
    auto alloch = [&](size_t n) { __half* p = (__half*)(wsb + off); off += ((n * 2 + 255) & ~(size_t)255); return p; };
    float*  h0    = allocf((size_t)N * 32);
    __half* hbuf  = alloch((size_t)N * 256);   // h1 uses N*128 halves; h2 uses N*256 halves
    float*  g1    = allocf((size_t)N * 64);
    float*  g2    = allocf((size_t)N * 128);
    float*  es    = allocf((size_t)N * 2);
    float*  ed    = allocf((size_t)N * 2);
    float*  sums  = allocf((size_t)G * 128);
    float*  cnts  = allocf((size_t)G);
    int* deg     = alloci((size_t)N);
    int* ofs     = alloci((size_t)N + 1);
    int* cursor  = alloci((size_t)N);
    int* sperm   = alloci((size_t)E);
    int* bsum    = alloci((size_t)nb);
    int* bofs    = alloci((size_t)nb);
    (void)ws_size;

    // init + CSR build (shared by both layers)
    init_kernel<<<(N + 255) / 256, 256, 0, stream>>>(deg, sums, cnts, N, G);
    hist_kernel<<<(E + 255) / 256, 256, 0, stream>>>(dst, deg, E);
    scan_blocks_kernel<<<nb, 256, 0, stream>>>(deg, ofs, bsum, N);
    scan_bsum_kernel<<<1, 1024, 0, stream>>>(bsum, bofs, ofs + N, nb);
    scan_add_kernel<<<nb, 256, 0, stream>>>(ofs, bofs, cursor, N);
    scatter_kernel<<<(E + 255) / 256, 256, 0, stream>>>(src, dst, cursor, sperm, E);

    // fc0
    fc0_kernel<<<(N + 7) / 8, 256, 0, stream>>>(x, fc0_w, fc0_b, h0, N);

    // ---- GAT layer 1 ----
    gat_transform1<<<(N + 7) / 8, 128, 0, stream>>>(h0, W1, a_src1, a_dst1, hbuf, es, ed, N);
    gat_agg1<<<(N + 3) / 4, 256, 0, stream>>>(ofs, sperm, es, ed, (const __half2*)hbuf, g1, N);

    // ---- GAT layer 2 ----
    gat_transform2<<<(N + 7) / 8, 256, 0, stream>>>(g1, b1, W2, a_src2, a_dst2, hbuf, es, ed, N);
    gat_agg2<<<(N + 3) / 4, 256, 0, stream>>>(ofs, sperm, es, ed, (const __half2*)hbuf, g2, N);

    // ---- pool + final linear ----
    pool_kernel<<<(N + POOL_NPB - 1) / POOL_NPB, 256, 0, stream>>>(g2, b2, batch, sums, cnts, N);
    final_kernel<<<G, 32, 0, stream>>>(sums, cnts, lo_w, lo_b, out, G);
}

// Round 5
// 429.970 us; speedup vs baseline: 2.8629x; 1.0987x over previous
//
#include <hip/hip_runtime.h>
#include <hip/hip_fp16.h>
#include <math.h>

#define NEG_SLOPE 0.2f
#define GAT_EPS 1e-16f

__device__ __forceinline__ float elu_f(float x) { return x > 0.f ? x : expm1f(x); }
__device__ __forceinline__ float lrelu_f(float x) { return x > 0.f ? x : NEG_SLOPE * x; }
__device__ __forceinline__ float neg_inf_f() { return __int_as_float(0xFF800000); }

typedef _Float16 half2v __attribute__((ext_vector_type(2)));

// fp32 accumulate of half2 dot: acc += v.x*a.x + v.y*a.y
__device__ __forceinline__ float fdot2f(unsigned int v, unsigned int a, float acc) {
#if __has_builtin(__builtin_amdgcn_fdot2)
    return __builtin_amdgcn_fdot2(__builtin_bit_cast(half2v, v),
                                  __builtin_bit_cast(half2v, a), acc, false);
#else
    __half2 hv = __builtin_bit_cast(__half2, v);
    __half2 ha = __builtin_bit_cast(__half2, a);
    float2 fv = __half22float2(hv), fa = __half22float2(ha);
    return fmaf(fv.x, fa.x, fmaf(fv.y, fa.y, acc));
#endif
}

__device__ __forceinline__ unsigned int pack_half2(float a, float b) {
    __half2 h = __floats2half2_rn(a, b);
    return __builtin_bit_cast(unsigned int, h);
}

__device__ __forceinline__ float waveReduceSum(float v) {
    #pragma unroll
    for (int off = 32; off > 0; off >>= 1) v += __shfl_xor(v, off, 64);
    return v;
}

// ---------------- init: zero deg, sums, cnts ----------------
__global__ void init_kernel(int* deg, float* sums, float* cnts, int N, int G) {
    int i = blockIdx.x * 256 + threadIdx.x;
    if (i < N) deg[i] = 0;
    if (i < G * 128) sums[i] = 0.f;
    if (i < G) cnts[i] = 0.f;
}

// ---------------- CSR build ----------------
__global__ __launch_bounds__(256) void hist_kernel(const int* __restrict__ dst,
                                                   int* __restrict__ deg, int E) {
    int e = blockIdx.x * 256 + threadIdx.x;
    if (e < E) atomicAdd(&deg[dst[e]], 1);
}

__global__ __launch_bounds__(256) void scan_blocks_kernel(const int* __restrict__ deg,
        int* __restrict__ ofs, int* __restrict__ bsum, int N) {
    __shared__ int wtot[4];
    int tid = threadIdx.x, lane = tid & 63, wid = tid >> 6;
    int i = blockIdx.x * 256 + tid;
    int v = (i < N) ? deg[i] : 0;
    int incl = v;
    #pragma unroll
    for (int off = 1; off < 64; off <<= 1) {
        int t = __shfl_up(incl, off, 64);
        if (lane >= off) incl += t;
    }
    if (lane == 63) wtot[wid] = incl;
    __syncthreads();
    int woff = 0;
    #pragma unroll
    for (int w = 0; w < 4; ++w) if (w < wid) woff += wtot[w];
    int excl = incl - v + woff;
    if (i < N) ofs[i] = excl;
    if (tid == 255) bsum[blockIdx.x] = woff + incl;
}

__global__ __launch_bounds__(1024) void scan_bsum_kernel(const int* __restrict__ bsum,
        int* __restrict__ bofs, int* __restrict__ ofsN, int nb) {
    __shared__ int wsum[16];
    int tid = threadIdx.x, lane = tid & 63, wid = tid >> 6;
    int v = (tid < nb) ? bsum[tid] : 0;
    int incl = v;
    #pragma unroll
    for (int off = 1; off < 64; off <<= 1) {
        int t = __shfl_up(incl, off, 64);
        if (lane >= off) incl += t;
    }
    if (lane == 63) wsum[wid] = incl;
    __syncthreads();
    if (wid == 0) {
        int wv = (lane < 16) ? wsum[lane] : 0;
        int winc = wv;
        #pragma unroll
        for (int off = 1; off < 16; off <<= 1) {
            int t = __shfl_up(winc, off, 64);
            if (lane >= off) winc += t;
        }
        if (lane < 16) wsum[lane] = winc - wv;
    }
    __syncthreads();
    int excl = incl - v + wsum[wid];
    if (tid < nb) bofs[tid] = excl;
    if (tid == nb - 1) *ofsN = excl + v;
}

__global__ __launch_bounds__(256) void scan_add_kernel(int* __restrict__ ofs,
        const int* __restrict__ bofs, int* __restrict__ cursor, int N) {
    int i = blockIdx.x * 256 + threadIdx.x;
    if (i < N) {
        int v = ofs[i] + bofs[blockIdx.x];
        ofs[i] = v;
        cursor[i] = v;
    }
}

__global__ __launch_bounds__(256) void scatter_kernel(
        const int* __restrict__ src, const int* __restrict__ dst,
        int* __restrict__ cursor, int* __restrict__ sperm, int E) {
    int e = blockIdx.x * 256 + threadIdx.x;
    if (e >= E) return;
    int d = dst[e];
    int pos = atomicAdd(&cursor[d], 1);
    sperm[pos] = src[e];
}

// ---------------- fused fc0 + GAT layer1 transform ----------------
// h0 = elu(x@W0+b0) in LDS; h1[N] fp16 packed (half idx n*128 + 2*o + h); es/ed.
// 256 thr: phase1 = 8 nodes x 32 ch; phase2 = 2 node-halves x 2 heads x 64 ch.
__global__ __launch_bounds__(256) void fused_t1(
        const float* __restrict__ x, const float* __restrict__ w0,
        const float* __restrict__ b0, const float* __restrict__ W1,
        const float* __restrict__ asrc, const float* __restrict__ adst,
        __half* __restrict__ h1, float* __restrict__ es, float* __restrict__ ed, int N) {
    __shared__ float xs[8 * 16];
    __shared__ float hs[8 * 32];
    int n0 = blockIdx.x * 8;
    int tid = threadIdx.x;
    if (tid < 128) {
        int gi = n0 * 16 + tid;
        xs[tid] = (gi < N * 16) ? x[gi] : 0.f;
    }
    __syncthreads();
    {
        int j = tid >> 5, o = tid & 31;
        float acc = b0[o];
        #pragma unroll
        for (int c = 0; c < 16; ++c) acc = fmaf(xs[j * 16 + c], w0[c * 32 + o], acc);
        hs[j * 32 + o] = elu_f(acc);
    }
    __syncthreads();
    int o = tid & 63, h = (tid >> 6) & 1, nh = tid >> 7;
    float acc[4];
    #pragma unroll
    for (int j = 0; j < 4; ++j) acc[j] = 0.f;
    const float* wp = W1 + h * (32 * 64) + o;
    #pragma unroll
    for (int c = 0; c < 32; ++c) {
        float wv = wp[c * 64];
        #pragma unroll
        for (int j = 0; j < 4; ++j) acc[j] = fmaf(hs[(nh * 4 + j) * 32 + c], wv, acc[j]);
    }
    float as = asrc[h * 64 + o], ad = adst[h * 64 + o];
    #pragma unroll
    for (int j = 0; j < 4; ++j) {
        int n = n0 + nh * 4 + j;
        if (n < N) h1[(size_t)n * 128 + 2 * o + h] = __float2half(acc[j]);
        float vs = waveReduceSum(acc[j] * as);
        float vd = waveReduceSum(acc[j] * ad);
        if (o == 0 && n < N) { es[n * 2 + h] = vs; ed[n * 2 + h] = vd; }
    }
}

// ---------------- GAT layer2 transform: h2 = g1 @ W2 (g1 pre-activated) ----------------
// h2 fp16 packed: half idx n*256 + 2*o + h
__global__ __launch_bounds__(256) void gat_transform2(
        const float* __restrict__ g1, const float* __restrict__ W,
        const float* __restrict__ asrc, const float* __restrict__ adst,
        __half* __restrict__ h2, float* __restrict__ es, float* __restrict__ ed, int N) {
    __shared__ float xs[8 * 64];
    __shared__ float esl[16], edl[16];
    int n0 = blockIdx.x * 8;
    int tid = threadIdx.x;
    for (int idx = tid; idx < 8 * 64; idx += 256) {
        int gi = n0 * 64 + idx;
        xs[idx] = (gi < N * 64) ? g1[gi] : 0.f;
    }
    if (tid < 16) { esl[tid] = 0.f; edl[tid] = 0.f; }
    __syncthreads();
    int h = tid >> 7, o = tid & 127, lane = tid & 63;
    float acc[8];
    #pragma unroll
    for (int j = 0; j < 8; ++j) acc[j] = 0.f;
    const float* wp = W + h * (64 * 128) + o;
    for (int c = 0; c < 64; ++c) {
        float wv = wp[c * 128];
        #pragma unroll
        for (int j = 0; j < 8; ++j) acc[j] = fmaf(xs[j * 64 + c], wv, acc[j]);
    }
    float as = asrc[h * 128 + o], ad = adst[h * 128 + o];
    #pragma unroll
    for (int j = 0; j < 8; ++j) {
        int n = n0 + j;
        if (n < N) h2[(size_t)n * 256 + 2 * o + h] = __float2half(acc[j]);
        float vs = waveReduceSum(acc[j] * as);
        float vd = waveReduceSum(acc[j] * ad);
        if (lane == 0) { atomicAdd(&esl[j * 2 + h], vs); atomicAdd(&edl[j * 2 + h], vd); }
    }
    __syncthreads();
    if (tid < 16) {
        int j = tid >> 1, hh = tid & 1, n = n0 + j;
        if (n < N) { es[n * 2 + hh] = esl[tid]; ed[n * 2 + hh] = edl[tid]; }
    }
}

// ---------------- aggregation layer1: one wave per dst node ----------------
// h1 rows: 64 uint (half2: .x=head0,.y=head1 per channel). g1 stores elu(acc+b1).
__global__ __launch_bounds__(256) void gat_agg1(
        const int* __restrict__ ofs, const int* __restrict__ sperm,
        const float* __restrict__ es, const float* __restrict__ ed,
        const unsigned int* __restrict__ h1, const float* __restrict__ b1,
        float* __restrict__ g1, int N) {
    int d = blockIdx.x * 4 + (threadIdx.x >> 6);
    if (d >= N) return;
    int lane = threadIdx.x & 63;
    int beg = ofs[d], end = ofs[d + 1];
    int deg = end - beg;
    float2 edv = *reinterpret_cast<const float2*>(ed + (size_t)d * 2);

    int s_f = 0;
    float e0f = neg_inf_f(), e1f = neg_inf_f();
    float m0 = neg_inf_f(), m1 = neg_inf_f();
    int i0 = beg + lane;
    if (i0 < end) {
        s_f = sperm[i0];
        float2 esv = *reinterpret_cast<const float2*>(es + (size_t)s_f * 2);
        e0f = lrelu_f(esv.x + edv.x);
        e1f = lrelu_f(esv.y + edv.y);
        m0 = e0f; m1 = e1f;
    }
    for (int i = i0 + 64; i < end; i += 64) {
        int s = sperm[i];
        float2 esv = *reinterpret_cast<const float2*>(es + (size_t)s * 2);
        m0 = fmaxf(m0, lrelu_f(esv.x + edv.x));
        m1 = fmaxf(m1, lrelu_f(esv.y + edv.y));
    }
    #pragma unroll
    for (int off = 32; off > 0; off >>= 1) {
        m0 = fmaxf(m0, __shfl_xor(m0, off, 64));
        m1 = fmaxf(m1, __shfl_xor(m1, off, 64));
    }
    float s0 = 0.f, s1 = 0.f;
    if (i0 < end) { s0 = __expf(e0f - m0); s1 = __expf(e1f - m1); }
    for (int i = i0 + 64; i < end; i += 64) {
        int s = sperm[i];
        float2 esv = *reinterpret_cast<const float2*>(es + (size_t)s * 2);
        s0 += __expf(lrelu_f(esv.x + edv.x) - m0);
        s1 += __expf(lrelu_f(esv.y + edv.y) - m1);
    }
    s0 = waveReduceSum(s0);
    s1 = waveReduceSum(s1);
    float r0 = 0.5f / (s0 + GAT_EPS), r1 = 0.5f / (s1 + GAT_EPS);
    unsigned int apack = pack_half2(__expf(e0f - m0) * r0, __expf(e1f - m1) * r1);

    float acc = 0.f;
    int jmax = deg < 64 ? deg : 64;
    for (int j = 0; j < jmax; ++j) {
        int s = __shfl(s_f, j, 64);
        unsigned int ap = (unsigned int)__shfl((int)apack, j, 64);
        acc = fdot2f(h1[(size_t)s * 64 + lane], ap, acc);
    }
    for (int i = beg + 64; i < end; ++i) {  // rare: deg > 64
        int s = sperm[i];
        float2 esv = *reinterpret_cast<const float2*>(es + (size_t)s * 2);
        float a0 = __expf(lrelu_f(esv.x + edv.x) - m0) * r0;
        float a1 = __expf(lrelu_f(esv.y + edv.y) - m1) * r1;
        acc = fdot2f(h1[(size_t)s * 64 + lane], pack_half2(a0, a1), acc);
    }
    g1[(size_t)d * 64 + lane] = elu_f(acc + b1[lane]);   // pre-activate for transform2
}

// ---------------- aggregation layer2: one wave per dst node, 2 channels/lane ----------------
// h2 rows: 64 uint2 (channels 2*lane, 2*lane+1, both heads). g2 stores elu(acc+b2).
__global__ __launch_bounds__(256) void gat_agg2(
        const int* __restrict__ ofs, const int* __restrict__ sperm,
        const float* __restrict__ es, const float* __restrict__ ed,
        const uint2* __restrict__ h2, const float* __restrict__ b2,
        float* __restrict__ g2, int N) {
    int d = blockIdx.x * 4 + (threadIdx.x >> 6);
    if (d >= N) return;
    int lane = threadIdx.x & 63;
    int beg = ofs[d], end = ofs[d + 1];
    int deg = end - beg;
    float2 edv = *reinterpret_cast<const float2*>(ed + (size_t)d * 2);

    int s_f = 0;
    float e0f = neg_inf_f(), e1f = neg_inf_f();
    float m0 = neg_inf_f(), m1 = neg_inf_f();
    int i0 = beg + lane;
    if (i0 < end) {
        s_f = sperm[i0];
        float2 esv = *reinterpret_cast<const float2*>(es + (size_t)s_f * 2);
        e0f = lrelu_f(esv.x + edv.x);
        e1f = lrelu_f(esv.y + edv.y);
        m0 = e0f; m1 = e1f;
    }
    for (int i = i0 + 64; i < end; i += 64) {
        int s = sperm[i];
        float2 esv = *reinterpret_cast<const float2*>(es + (size_t)s * 2);
        m0 = fmaxf(m0, lrelu_f(esv.x + edv.x));
        m1 = fmaxf(m1, lrelu_f(esv.y + edv.y));
    }
    #pragma unroll
    for (int off = 32; off > 0; off >>= 1) {
        m0 = fmaxf(m0, __shfl_xor(m0, off, 64));
        m1 = fmaxf(m1, __shfl_xor(m1, off, 64));
    }
    float s0 = 0.f, s1 = 0.f;
    if (i0 < end) { s0 = __expf(e0f - m0); s1 = __expf(e1f - m1); }
    for (int i = i0 + 64; i < end; i += 64) {
        int s = sperm[i];
        float2 esv = *reinterpret_cast<const float2*>(es + (size_t)s * 2);
        s0 += __expf(lrelu_f(esv.x + edv.x) - m0);
        s1 += __expf(lrelu_f(esv.y + edv.y) - m1);
    }
    s0 = waveReduceSum(s0);
    s1 = waveReduceSum(s1);
    float r0 = 0.5f / (s0 + GAT_EPS), r1 = 0.5f / (s1 + GAT_EPS);
    unsigned int apack = pack_half2(__expf(e0f - m0) * r0, __expf(e1f - m1) * r1);

    float acc0 = 0.f, acc1 = 0.f;   // channels 2*lane, 2*lane+1
    int jmax = deg < 64 ? deg : 64;
    for (int j = 0; j < jmax; ++j) {
        int s = __shfl(s_f, j, 64);
        unsigned int ap = (unsigned int)__shfl((int)apack, j, 64);
        uint2 v = h2[(size_t)s * 64 + lane];
        acc0 = fdot2f(v.x, ap, acc0);
        acc1 = fdot2f(v.y, ap, acc1);
    }
    for (int i = beg + 64; i < end; ++i) {  // rare: deg > 64
        int s = sperm[i];
        float2 esv = *reinterpret_cast<const float2*>(es + (size_t)s * 2);
        float a0 = __expf(lrelu_f(esv.x + edv.x) - m0) * r0;
        float a1 = __expf(lrelu_f(esv.y + edv.y) - m1) * r1;
        unsigned int ap = pack_half2(a0, a1);
        uint2 v = h2[(size_t)s * 64 + lane];
        acc0 = fdot2f(v.x, ap, acc0);
        acc1 = fdot2f(v.y, ap, acc1);
    }
    float2 bv = reinterpret_cast<const float2*>(b2)[lane];
    g2[(size_t)d * 128 + 2 * lane]     = elu_f(acc0 + bv.x);   // pre-activated for pool
    g2[(size_t)d * 128 + 2 * lane + 1] = elu_f(acc1 + bv.y);
}

// ---------------- pool: sorted-batch run accumulation (g2 pre-activated) ----------------
#define POOL_NPB 128
__global__ __launch_bounds__(256) void pool_kernel(
        const float* __restrict__ g2, const int* __restrict__ batch,
        float* __restrict__ sums, float* __restrict__ cnts, int N) {
    int n0 = blockIdx.x * POOL_NPB;
    int c = threadIdx.x & 127;
    int p = threadIdx.x >> 7;
    int nend = n0 + POOL_NPB; if (nend > N) nend = N;
    int n = n0 + p;
    if (n >= nend) return;
    int cur_b = batch[n];
    float acc = 0.f;
    int cnt = 0;
    for (; n < nend; n += 2) {
        int b = batch[n];
        if (b != cur_b) {
            atomicAdd(&sums[(size_t)cur_b * 128 + c], acc);
            if (c == 0) atomicAdd(&cnts[cur_b], (float)cnt);
            acc = 0.f; cnt = 0; cur_b = b;
        }
        acc += g2[(size_t)n * 128 + c];
        ++cnt;
    }
    atomicAdd(&sums[(size_t)cur_b * 128 + c], acc);
    if (c == 0) atomicAdd(&cnts[cur_b], (float)cnt);
}

// ---------------- final: out = (sums/cnt) @ lo_w + lo_b ----------------
__global__ void final_kernel(
        const float* __restrict__ sums, const float* __restrict__ cnts,
        const float* __restrict__ w, const float* __restrict__ b,
        float* __restrict__ out, int G) {
    int g = blockIdx.x;
    int k = threadIdx.x;
    if (k >= 24) return;
    float inv = 1.f / fmaxf(cnts[g], 1.f);
    float acc = b[k];
    #pragma unroll
    for (int c = 0; c < 128; ++c) acc = fmaf(sums[g * 128 + c] * inv, w[c * 24 + k], acc);
    out[g * 24 + k] = acc;
}

extern "C" void kernel_launch(void* const* d_in, const int* in_sizes, int n_in,
                              void* d_out, int out_size, void* d_ws, size_t ws_size,
                              hipStream_t stream) {
    const float* x      = (const float*)d_in[0];
    const int*   ei     = (const int*)d_in[1];
    const int*   batch  = (const int*)d_in[2];
    const float* fc0_w  = (const float*)d_in[3];
    const float* fc0_b  = (const float*)d_in[4];
    const float* W1     = (const float*)d_in[5];
    const float* a_src1 = (const float*)d_in[6];
    const float* a_dst1 = (const float*)d_in[7];
    const float* b1     = (const float*)d_in[8];
    const float* W2     = (const float*)d_in[9];
    const float* a_src2 = (const float*)d_in[10];
    const float* a_dst2 = (const float*)d_in[11];
    const float* b2     = (const float*)d_in[12];
    const float* lo_w   = (const float*)d_in[13];
    const float* lo_b   = (const float*)d_in[14];
    float* out = (float*)d_out;

    const int N = in_sizes[0] / 16;
    const int E = in_sizes[1] / 2;
    const int G = out_size / 24;
    const int* src = ei;
    const int* dst = ei + E;
    const int nb = (N + 255) / 256;

    char* wsb = (char*)d_ws;
    size_t off = 0;
    auto allocf = [&](size_t n) { float* p = (float*)(wsb + off); off += ((n * 4 + 255) & ~(size_t)255); return p; };
    auto alloci = [&](size_t n) { int* p = (int*)(wsb + off); off += ((n * 4 + 255) & ~(size_t)255); return p; };
    auto alloch = [&](size_t n) { __half* p = (__half*)(wsb + off); off += ((n * 2 + 255) & ~(size_t)255); return p; };
    __half* hbuf  = alloch((size_t)N * 256);   // h1 uses N*128 halves; h2 uses N*256 halves
    float*  g1    = allocf((size_t)N * 64);
    float*  g2    = allocf((size_t)N * 128);
    float*  es    = allocf((size_t)N * 2);
    float*  ed    = allocf((size_t)N * 2);
    float*  sums  = allocf((size_t)G * 128);
    float*  cnts  = allocf((size_t)G);
    int* deg     = alloci((size_t)N);
    int* ofs     = alloci((size_t)N + 1);
    int* cursor  = alloci((size_t)N);
    int* sperm   = alloci((size_t)E);
    int* bsum    = alloci((size_t)nb);
    int* bofs    = alloci((size_t)nb);
    (void)ws_size;

    // init + CSR build (shared by both layers)
    init_kernel<<<(N + 255) / 256, 256, 0, stream>>>(deg, sums, cnts, N, G);
    hist_kernel<<<(E + 255) / 256, 256, 0, stream>>>(dst, deg, E);
    scan_blocks_kernel<<<nb, 256, 0, stream>>>(deg, ofs, bsum, N);
    scan_bsum_kernel<<<1, 1024, 0, stream>>>(bsum, bofs, ofs + N, nb);
    scan_add_kernel<<<nb, 256, 0, stream>>>(ofs, bofs, cursor, N);
    scatter_kernel<<<(E + 255) / 256, 256, 0, stream>>>(src, dst, cursor, sperm, E);

    // ---- GAT layer 1 (fc0 fused into transform) ----
    fused_t1<<<(N + 7) / 8, 256, 0, stream>>>(x, fc0_w, fc0_b, W1, a_src1, a_dst1, hbuf, es, ed, N);
    gat_agg1<<<(N + 3) / 4, 256, 0, stream>>>(ofs, sperm, es, ed, (const unsigned int*)hbuf, b1, g1, N);

    // ---- GAT layer 2 ----
    gat_transform2<<<(N + 7) / 8, 256, 0, stream>>>(g1, W2, a_src2, a_dst2, hbuf, es, ed, N);
    gat_agg2<<<(N + 3) / 4, 256, 0, stream>>>(ofs, sperm, es, ed, (const uint2*)hbuf, b2, g2, N);

    // ---- pool + final linear ----
    pool_kernel<<<(N + POOL_NPB - 1) / POOL_NPB, 256, 0, stream>>>(g2, batch, sums, cnts, N);
    final_kernel<<<G, 32, 0, stream>>>(sums, cnts, lo_w, lo_b, out, G);
}

// Round 6
// 392.667 us; speedup vs baseline: 3.1349x; 1.0950x over previous
//
#include <hip/hip_runtime.h>
#include <hip/hip_fp16.h>
#include <math.h>

#define NEG_SLOPE 0.2f
#define GAT_EPS 1e-16f

__device__ __forceinline__ float elu_f(float x) { return x > 0.f ? x : expm1f(x); }
__device__ __forceinline__ float lrelu_f(float x) { return x > 0.f ? x : NEG_SLOPE * x; }
__device__ __forceinline__ float neg_inf_f() { return __int_as_float(0xFF800000); }

typedef _Float16 half2v __attribute__((ext_vector_type(2)));

// fp32 accumulate of half2 dot: acc += v.x*a.x + v.y*a.y
__device__ __forceinline__ float fdot2f(unsigned int v, unsigned int a, float acc) {
#if __has_builtin(__builtin_amdgcn_fdot2)
    return __builtin_amdgcn_fdot2(__builtin_bit_cast(half2v, v),
                                  __builtin_bit_cast(half2v, a), acc, false);
#else
    __half2 hv = __builtin_bit_cast(__half2, v);
    __half2 ha = __builtin_bit_cast(__half2, a);
    float2 fv = __half22float2(hv), fa = __half22float2(ha);
    return fmaf(fv.x, fa.x, fmaf(fv.y, fa.y, acc));
#endif
}

__device__ __forceinline__ unsigned int pack_half2(float a, float b) {
    __half2 h = __floats2half2_rn(a, b);
    return __builtin_bit_cast(unsigned int, h);
}

__device__ __forceinline__ float waveReduceSum(float v) {
    #pragma unroll
    for (int off = 32; off > 0; off >>= 1) v += __shfl_xor(v, off, 64);
    return v;
}

// ---------------- init: zero deg, sums, cnts ----------------
__global__ void init_kernel(int* deg, float* sums, float* cnts, int N, int G) {
    int i = blockIdx.x * 256 + threadIdx.x;
    if (i < N) deg[i] = 0;
    if (i < G * 128) sums[i] = 0.f;
    if (i < G) cnts[i] = 0.f;
}

// ---------------- CSR build ----------------
__global__ __launch_bounds__(256) void hist_kernel(const int* __restrict__ dst,
                                                   int* __restrict__ deg, int E) {
    int e = blockIdx.x * 256 + threadIdx.x;
    if (e < E) atomicAdd(&deg[dst[e]], 1);
}

__global__ __launch_bounds__(256) void scan_blocks_kernel(const int* __restrict__ deg,
        int* __restrict__ ofs, int* __restrict__ bsum, int N) {
    __shared__ int wtot[4];
    int tid = threadIdx.x, lane = tid & 63, wid = tid >> 6;
    int i = blockIdx.x * 256 + tid;
    int v = (i < N) ? deg[i] : 0;
    int incl = v;
    #pragma unroll
    for (int off = 1; off < 64; off <<= 1) {
        int t = __shfl_up(incl, off, 64);
        if (lane >= off) incl += t;
    }
    if (lane == 63) wtot[wid] = incl;
    __syncthreads();
    int woff = 0;
    #pragma unroll
    for (int w = 0; w < 4; ++w) if (w < wid) woff += wtot[w];
    int excl = incl - v + woff;
    if (i < N) ofs[i] = excl;
    if (tid == 255) bsum[blockIdx.x] = woff + incl;
}

__global__ __launch_bounds__(1024) void scan_bsum_kernel(const int* __restrict__ bsum,
        int* __restrict__ bofs, int* __restrict__ ofsN, int nb) {
    __shared__ int wsum[16];
    int tid = threadIdx.x, lane = tid & 63, wid = tid >> 6;
    int v = (tid < nb) ? bsum[tid] : 0;
    int incl = v;
    #pragma unroll
    for (int off = 1; off < 64; off <<= 1) {
        int t = __shfl_up(incl, off, 64);
        if (lane >= off) incl += t;
    }
    if (lane == 63) wsum[wid] = incl;
    __syncthreads();
    if (wid == 0) {
        int wv = (lane < 16) ? wsum[lane] : 0;
        int winc = wv;
        #pragma unroll
        for (int off = 1; off < 16; off <<= 1) {
            int t = __shfl_up(winc, off, 64);
            if (lane >= off) winc += t;
        }
        if (lane < 16) wsum[lane] = winc - wv;
    }
    __syncthreads();
    int excl = incl - v + wsum[wid];
    if (tid < nb) bofs[tid] = excl;
    if (tid == nb - 1) *ofsN = excl + v;
}

__global__ __launch_bounds__(256) void scan_add_kernel(int* __restrict__ ofs,
        const int* __restrict__ bofs, int* __restrict__ cursor, int N) {
    int i = blockIdx.x * 256 + threadIdx.x;
    if (i < N) {
        int v = ofs[i] + bofs[blockIdx.x];
        ofs[i] = v;
        cursor[i] = v;
    }
}

__global__ __launch_bounds__(256) void scatter_kernel(
        const int* __restrict__ src, const int* __restrict__ dst,
        int* __restrict__ cursor, int* __restrict__ sperm, int E) {
    int e = blockIdx.x * 256 + threadIdx.x;
    if (e >= E) return;
    int d = dst[e];
    int pos = atomicAdd(&cursor[d], 1);
    sperm[pos] = src[e];
}

// ---------------- fused fc0 + GAT layer1 transform ----------------
__global__ __launch_bounds__(256) void fused_t1(
        const float* __restrict__ x, const float* __restrict__ w0,
        const float* __restrict__ b0, const float* __restrict__ W1,
        const float* __restrict__ asrc, const float* __restrict__ adst,
        __half* __restrict__ h1, float* __restrict__ es, float* __restrict__ ed, int N) {
    __shared__ float xs[8 * 16];
    __shared__ float hs[8 * 32];
    int n0 = blockIdx.x * 8;
    int tid = threadIdx.x;
    if (tid < 128) {
        int gi = n0 * 16 + tid;
        xs[tid] = (gi < N * 16) ? x[gi] : 0.f;
    }
    __syncthreads();
    {
        int j = tid >> 5, o = tid & 31;
        float acc = b0[o];
        #pragma unroll
        for (int c = 0; c < 16; ++c) acc = fmaf(xs[j * 16 + c], w0[c * 32 + o], acc);
        hs[j * 32 + o] = elu_f(acc);
    }
    __syncthreads();
    int o = tid & 63, h = (tid >> 6) & 1, nh = tid >> 7;
    float acc[4];
    #pragma unroll
    for (int j = 0; j < 4; ++j) acc[j] = 0.f;
    const float* wp = W1 + h * (32 * 64) + o;
    #pragma unroll
    for (int c = 0; c < 32; ++c) {
        float wv = wp[c * 64];
        #pragma unroll
        for (int j = 0; j < 4; ++j) acc[j] = fmaf(hs[(nh * 4 + j) * 32 + c], wv, acc[j]);
    }
    float as = asrc[h * 64 + o], ad = adst[h * 64 + o];
    #pragma unroll
    for (int j = 0; j < 4; ++j) {
        int n = n0 + nh * 4 + j;
        if (n < N) h1[(size_t)n * 128 + 2 * o + h] = __float2half(acc[j]);
        float vs = waveReduceSum(acc[j] * as);
        float vd = waveReduceSum(acc[j] * ad);
        if (o == 0 && n < N) { es[n * 2 + h] = vs; ed[n * 2 + h] = vd; }
    }
}

// ---------------- GAT layer2 transform: h2 = g1 @ W2 (g1 pre-activated) ----------------
__global__ __launch_bounds__(256) void gat_transform2(
        const float* __restrict__ g1, const float* __restrict__ W,
        const float* __restrict__ asrc, const float* __restrict__ adst,
        __half* __restrict__ h2, float* __restrict__ es, float* __restrict__ ed, int N) {
    __shared__ float xs[8 * 64];
    __shared__ float esl[16], edl[16];
    int n0 = blockIdx.x * 8;
    int tid = threadIdx.x;
    for (int idx = tid; idx < 8 * 64; idx += 256) {
        int gi = n0 * 64 + idx;
        xs[idx] = (gi < N * 64) ? g1[gi] : 0.f;
    }
    if (tid < 16) { esl[tid] = 0.f; edl[tid] = 0.f; }
    __syncthreads();
    int h = tid >> 7, o = tid & 127, lane = tid & 63;
    float acc[8];
    #pragma unroll
    for (int j = 0; j < 8; ++j) acc[j] = 0.f;
    const float* wp = W + h * (64 * 128) + o;
    for (int c = 0; c < 64; ++c) {
        float wv = wp[c * 128];
        #pragma unroll
        for (int j = 0; j < 8; ++j) acc[j] = fmaf(xs[j * 64 + c], wv, acc[j]);
    }
    float as = asrc[h * 128 + o], ad = adst[h * 128 + o];
    #pragma unroll
    for (int j = 0; j < 8; ++j) {
        int n = n0 + j;
        if (n < N) h2[(size_t)n * 256 + 2 * o + h] = __float2half(acc[j]);
        float vs = waveReduceSum(acc[j] * as);
        float vd = waveReduceSum(acc[j] * ad);
        if (lane == 0) { atomicAdd(&esl[j * 2 + h], vs); atomicAdd(&edl[j * 2 + h], vd); }
    }
    __syncthreads();
    if (tid < 16) {
        int j = tid >> 1, hh = tid & 1, n = n0 + j;
        if (n < N) { es[n * 2 + hh] = esl[tid]; ed[n * 2 + hh] = edl[tid]; }
    }
}

// ---------------- aggregation layer1: one wave per dst node ----------------
// h1 rows: 64 uint (half2 .x=head0,.y=head1). meta in LDS: (src, alpha-pack) per edge.
__global__ __launch_bounds__(256) void gat_agg1(
        const int* __restrict__ ofs, const int* __restrict__ sperm,
        const float* __restrict__ es, const float* __restrict__ ed,
        const unsigned int* __restrict__ h1, const float* __restrict__ b1,
        float* __restrict__ g1, int N) {
    __shared__ uint2 meta[4][64];
    int w = threadIdx.x >> 6;
    int d = blockIdx.x * 4 + w;
    if (d >= N) return;
    int lane = threadIdx.x & 63;
    int beg = ofs[d], end = ofs[d + 1];
    int deg = end - beg;
    float2 edv = *reinterpret_cast<const float2*>(ed + (size_t)d * 2);

    int s_f = 0;
    float e0f = neg_inf_f(), e1f = neg_inf_f();
    float m0 = neg_inf_f(), m1 = neg_inf_f();
    int i0 = beg + lane;
    if (i0 < end) {
        s_f = sperm[i0];
        float2 esv = *reinterpret_cast<const float2*>(es + (size_t)s_f * 2);
        e0f = lrelu_f(esv.x + edv.x);
        e1f = lrelu_f(esv.y + edv.y);
        m0 = e0f; m1 = e1f;
    }
    for (int i = i0 + 64; i < end; i += 64) {
        int s = sperm[i];
        float2 esv = *reinterpret_cast<const float2*>(es + (size_t)s * 2);
        m0 = fmaxf(m0, lrelu_f(esv.x + edv.x));
        m1 = fmaxf(m1, lrelu_f(esv.y + edv.y));
    }
    #pragma unroll
    for (int off = 32; off > 0; off >>= 1) {
        m0 = fmaxf(m0, __shfl_xor(m0, off, 64));
        m1 = fmaxf(m1, __shfl_xor(m1, off, 64));
    }
    float s0 = 0.f, s1 = 0.f;
    if (i0 < end) { s0 = __expf(e0f - m0); s1 = __expf(e1f - m1); }
    for (int i = i0 + 64; i < end; i += 64) {
        int s = sperm[i];
        float2 esv = *reinterpret_cast<const float2*>(es + (size_t)s * 2);
        s0 += __expf(lrelu_f(esv.x + edv.x) - m0);
        s1 += __expf(lrelu_f(esv.y + edv.y) - m1);
    }
    s0 = waveReduceSum(s0);
    s1 = waveReduceSum(s1);
    float r0 = 0.5f / (s0 + GAT_EPS), r1 = 0.5f / (s1 + GAT_EPS);
    int jmax = deg < 64 ? deg : 64;
    if (lane < jmax)
        meta[w][lane] = make_uint2((unsigned int)s_f,
                                   pack_half2(__expf(e0f - m0) * r0, __expf(e1f - m1) * r1));
    // wave-internal LDS write->read; compiler inserts lgkmcnt wait, no barrier needed

    float acc = 0.f;
    int j = 0;
    for (; j + 4 <= jmax; j += 4) {
        uint2 m0_ = meta[w][j + 0];
        uint2 m1_ = meta[w][j + 1];
        uint2 m2_ = meta[w][j + 2];
        uint2 m3_ = meta[w][j + 3];
        unsigned int v0 = h1[(size_t)m0_.x * 64 + lane];
        unsigned int v1 = h1[(size_t)m1_.x * 64 + lane];
        unsigned int v2 = h1[(size_t)m2_.x * 64 + lane];
        unsigned int v3 = h1[(size_t)m3_.x * 64 + lane];
        acc = fdot2f(v0, m0_.y, acc);
        acc = fdot2f(v1, m1_.y, acc);
        acc = fdot2f(v2, m2_.y, acc);
        acc = fdot2f(v3, m3_.y, acc);
    }
    for (; j < jmax; ++j) {
        uint2 m = meta[w][j];
        acc = fdot2f(h1[(size_t)m.x * 64 + lane], m.y, acc);
    }
    for (int i = beg + 64; i < end; ++i) {  // rare: deg > 64
        int s = sperm[i];
        float2 esv = *reinterpret_cast<const float2*>(es + (size_t)s * 2);
        float a0 = __expf(lrelu_f(esv.x + edv.x) - m0) * r0;
        float a1 = __expf(lrelu_f(esv.y + edv.y) - m1) * r1;
        acc = fdot2f(h1[(size_t)s * 64 + lane], pack_half2(a0, a1), acc);
    }
    g1[(size_t)d * 64 + lane] = elu_f(acc + b1[lane]);   // pre-activate for transform2
}

// ---------------- aggregation layer2: one wave per dst node, 2 channels/lane ----------------
__global__ __launch_bounds__(256) void gat_agg2(
        const int* __restrict__ ofs, const int* __restrict__ sperm,
        const float* __restrict__ es, const float* __restrict__ ed,
        const uint2* __restrict__ h2, const float* __restrict__ b2,
        float* __restrict__ g2, int N) {
    __shared__ uint2 meta[4][64];
    int w = threadIdx.x >> 6;
    int d = blockIdx.x * 4 + w;
    if (d >= N) return;
    int lane = threadIdx.x & 63;
    int beg = ofs[d], end = ofs[d + 1];
    int deg = end - beg;
    float2 edv = *reinterpret_cast<const float2*>(ed + (size_t)d * 2);

    int s_f = 0;
    float e0f = neg_inf_f(), e1f = neg_inf_f();
    float m0 = neg_inf_f(), m1 = neg_inf_f();
    int i0 = beg + lane;
    if (i0 < end) {
        s_f = sperm[i0];
        float2 esv = *reinterpret_cast<const float2*>(es + (size_t)s_f * 2);
        e0f = lrelu_f(esv.x + edv.x);
        e1f = lrelu_f(esv.y + edv.y);
        m0 = e0f; m1 = e1f;
    }
    for (int i = i0 + 64; i < end; i += 64) {
        int s = sperm[i];
        float2 esv = *reinterpret_cast<const float2*>(es + (size_t)s * 2);
        m0 = fmaxf(m0, lrelu_f(esv.x + edv.x));
        m1 = fmaxf(m1, lrelu_f(esv.y + edv.y));
    }
    #pragma unroll
    for (int off = 32; off > 0; off >>= 1) {
        m0 = fmaxf(m0, __shfl_xor(m0, off, 64));
        m1 = fmaxf(m1, __shfl_xor(m1, off, 64));
    }
    float s0 = 0.f, s1 = 0.f;
    if (i0 < end) { s0 = __expf(e0f - m0); s1 = __expf(e1f - m1); }
    for (int i = i0 + 64; i < end; i += 64) {
        int s = sperm[i];
        float2 esv = *reinterpret_cast<const float2*>(es + (size_t)s * 2);
        s0 += __expf(lrelu_f(esv.x + edv.x) - m0);
        s1 += __expf(lrelu_f(esv.y + edv.y) - m1);
    }
    s0 = waveReduceSum(s0);
    s1 = waveReduceSum(s1);
    float r0 = 0.5f / (s0 + GAT_EPS), r1 = 0.5f / (s1 + GAT_EPS);
    int jmax = deg < 64 ? deg : 64;
    if (lane < jmax)
        meta[w][lane] = make_uint2((unsigned int)s_f,
                                   pack_half2(__expf(e0f - m0) * r0, __expf(e1f - m1) * r1));

    float acc0 = 0.f, acc1 = 0.f;   // channels 2*lane, 2*lane+1
    int j = 0;
    for (; j + 4 <= jmax; j += 4) {
        uint2 m0_ = meta[w][j + 0];
        uint2 m1_ = meta[w][j + 1];
        uint2 m2_ = meta[w][j + 2];
        uint2 m3_ = meta[w][j + 3];
        uint2 v0 = h2[(size_t)m0_.x * 64 + lane];
        uint2 v1 = h2[(size_t)m1_.x * 64 + lane];
        uint2 v2 = h2[(size_t)m2_.x * 64 + lane];
        uint2 v3 = h2[(size_t)m3_.x * 64 + lane];
        acc0 = fdot2f(v0.x, m0_.y, acc0); acc1 = fdot2f(v0.y, m0_.y, acc1);
        acc0 = fdot2f(v1.x, m1_.y, acc0); acc1 = fdot2f(v1.y, m1_.y, acc1);
        acc0 = fdot2f(v2.x, m2_.y, acc0); acc1 = fdot2f(v2.y, m2_.y, acc1);
        acc0 = fdot2f(v3.x, m3_.y, acc0); acc1 = fdot2f(v3.y, m3_.y, acc1);
    }
    for (; j < jmax; ++j) {
        uint2 m = meta[w][j];
        uint2 v = h2[(size_t)m.x * 64 + lane];
        acc0 = fdot2f(v.x, m.y, acc0);
        acc1 = fdot2f(v.y, m.y, acc1);
    }
    for (int i = beg + 64; i < end; ++i) {  // rare: deg > 64
        int s = sperm[i];
        float2 esv = *reinterpret_cast<const float2*>(es + (size_t)s * 2);
        float a0 = __expf(lrelu_f(esv.x + edv.x) - m0) * r0;
        float a1 = __expf(lrelu_f(esv.y + edv.y) - m1) * r1;
        unsigned int ap = pack_half2(a0, a1);
        uint2 v = h2[(size_t)s * 64 + lane];
        acc0 = fdot2f(v.x, ap, acc0);
        acc1 = fdot2f(v.y, ap, acc1);
    }
    float2 bv = reinterpret_cast<const float2*>(b2)[lane];
    g2[(size_t)d * 128 + 2 * lane]     = elu_f(acc0 + bv.x);   // pre-activated for pool
    g2[(size_t)d * 128 + 2 * lane + 1] = elu_f(acc1 + bv.y);
}

// ---------------- pool: sorted-batch run accumulation (g2 pre-activated) ----------------
#define POOL_NPB 128
__global__ __launch_bounds__(256) void pool_kernel(
        const float* __restrict__ g2, const int* __restrict__ batch,
        float* __restrict__ sums, float* __restrict__ cnts, int N) {
    int n0 = blockIdx.x * POOL_NPB;
    int c = threadIdx.x & 127;
    int p = threadIdx.x >> 7;
    int nend = n0 + POOL_NPB; if (nend > N) nend = N;
    int n = n0 + p;
    if (n >= nend) return;
    int cur_b = batch[n];
    float acc = 0.f;
    int cnt = 0;
    for (; n < nend; n += 2) {
        int b = batch[n];
        if (b != cur_b) {
            atomicAdd(&sums[(size_t)cur_b * 128 + c], acc);
            if (c == 0) atomicAdd(&cnts[cur_b], (float)cnt);
            acc = 0.f; cnt = 0; cur_b = b;
        }
        acc += g2[(size_t)n * 128 + c];
        ++cnt;
    }
    atomicAdd(&sums[(size_t)cur_b * 128 + c], acc);
    if (c == 0) atomicAdd(&cnts[cur_b], (float)cnt);
}

// ---------------- final: out = (sums/cnt) @ lo_w + lo_b ----------------
__global__ void final_kernel(
        const float* __restrict__ sums, const float* __restrict__ cnts,
        const float* __restrict__ w, const float* __restrict__ b,
        float* __restrict__ out, int G) {
    int g = blockIdx.x;
    int k = threadIdx.x;
    if (k >= 24) return;
    float inv = 1.f / fmaxf(cnts[g], 1.f);
    float acc = b[k];
    #pragma unroll
    for (int c = 0; c < 128; ++c) acc = fmaf(sums[g * 128 + c] * inv, w[c * 24 + k], acc);
    out[g * 24 + k] = acc;
}

extern "C" void kernel_launch(void* const* d_in, const int* in_sizes, int n_in,
                              void* d_out, int out_size, void* d_ws, size_t ws_size,
                              hipStream_t stream) {
    const float* x      = (const float*)d_in[0];
    const int*   ei     = (const int*)d_in[1];
    const int*   batch  = (const int*)d_in[2];
    const float* fc0_w  = (const float*)d_in[3];
    const float* fc0_b  = (const float*)d_in[4];
    const float* W1     = (const float*)d_in[5];
    const float* a_src1 = (const float*)d_in[6];
    const float* a_dst1 = (const float*)d_in[7];
    const float* b1     = (const float*)d_in[8];
    const float* W2     = (const float*)d_in[9];
    const float* a_src2 = (const float*)d_in[10];
    const float* a_dst2 = (const float*)d_in[11];
    const float* b2     = (const float*)d_in[12];
    const float* lo_w   = (const float*)d_in[13];
    const float* lo_b   = (const float*)d_in[14];
    float* out = (float*)d_out;

    const int N = in_sizes[0] / 16;
    const int E = in_sizes[1] / 2;
    const int G = out_size / 24;
    const int* src = ei;
    const int* dst = ei + E;
    const int nb = (N + 255) / 256;

    char* wsb = (char*)d_ws;
    size_t off = 0;
    auto allocf = [&](size_t n) { float* p = (float*)(wsb + off); off += ((n * 4 + 255) & ~(size_t)255); return p; };
    auto alloci = [&](size_t n) { int* p = (int*)(wsb + off); off += ((n * 4 + 255) & ~(size_t)255); return p; };
    auto alloch = [&](size_t n) { __half* p = (__half*)(wsb + off); off += ((n * 2 + 255) & ~(size_t)255); return p; };
    __half* hbuf  = alloch((size_t)N * 256);   // h1 uses N*128 halves; h2 uses N*256 halves
    float*  g1    = allocf((size_t)N * 64);
    float*  g2    = allocf((size_t)N * 128);
    float*  es    = allocf((size_t)N * 2);
    float*  ed    = allocf((size_t)N * 2);
    float*  sums  = allocf((size_t)G * 128);
    float*  cnts  = allocf((size_t)G);
    int* deg     = alloci((size_t)N);
    int* ofs     = alloci((size_t)N + 1);
    int* cursor  = alloci((size_t)N);
    int* sperm   = alloci((size_t)E);
    int* bsum    = alloci((size_t)nb);
    int* bofs    = alloci((size_t)nb);
    (void)ws_size;

    // init + CSR build (shared by both layers)
    init_kernel<<<(N + 255) / 256, 256, 0, stream>>>(deg, sums, cnts, N, G);
    hist_kernel<<<(E + 255) / 256, 256, 0, stream>>>(dst, deg, E);
    scan_blocks_kernel<<<nb, 256, 0, stream>>>(deg, ofs, bsum, N);
    scan_bsum_kernel<<<1, 1024, 0, stream>>>(bsum, bofs, ofs + N, nb);
    scan_add_kernel<<<nb, 256, 0, stream>>>(ofs, bofs, cursor, N);
    scatter_kernel<<<(E + 255) / 256, 256, 0, stream>>>(src, dst, cursor, sperm, E);

    // ---- GAT layer 1 (fc0 fused into transform) ----
    fused_t1<<<(N + 7) / 8, 256, 0, stream>>>(x, fc0_w, fc0_b, W1, a_src1, a_dst1, hbuf, es, ed, N);
    gat_agg1<<<(N + 3) / 4, 256, 0, stream>>>(ofs, sperm, es, ed, (const unsigned int*)hbuf, b1, g1, N);

    // ---- GAT layer 2 ----
    gat_transform2<<<(N + 7) / 8, 256, 0, stream>>>(g1, W2, a_src2, a_dst2, hbuf, es, ed, N);
    gat_agg2<<<(N + 3) / 4, 256, 0, stream>>>(ofs, sperm, es, ed, (const uint2*)hbuf, b2, g2, N);

    // ---- pool + final linear ----
    pool_kernel<<<(N + POOL_NPB - 1) / POOL_NPB, 256, 0, stream>>>(g2, batch, sums, cnts, N);
    final_kernel<<<G, 32, 0, stream>>>(sums, cnts, lo_w, lo_b, out, G);
}

// Round 7
// 374.416 us; speedup vs baseline: 3.2877x; 1.0487x over previous
//
#include <hip/hip_runtime.h>
#include <hip/hip_fp16.h>
#include <math.h>

#define NEG_SLOPE 0.2f
#define GAT_EPS 1e-16f

__device__ __forceinline__ float elu_f(float x) { return x > 0.f ? x : expm1f(x); }
__device__ __forceinline__ float lrelu_f(float x) { return x > 0.f ? x : NEG_SLOPE * x; }
__device__ __forceinline__ float neg_inf_f() { return __int_as_float(0xFF800000); }

typedef _Float16 half2v __attribute__((ext_vector_type(2)));

// fp32 accumulate of half2 dot: acc += v.x*a.x + v.y*a.y
__device__ __forceinline__ float fdot2f(unsigned int v, unsigned int a, float acc) {
#if __has_builtin(__builtin_amdgcn_fdot2)
    return __builtin_amdgcn_fdot2(__builtin_bit_cast(half2v, v),
                                  __builtin_bit_cast(half2v, a), acc, false);
#else
    __half2 hv = __builtin_bit_cast(__half2, v);
    __half2 ha = __builtin_bit_cast(__half2, a);
    float2 fv = __half22float2(hv), fa = __half22float2(ha);
    return fmaf(fv.x, fa.x, fmaf(fv.y, fa.y, acc));
#endif
}

__device__ __forceinline__ unsigned int pack_half2(float a, float b) {
    __half2 h = __floats2half2_rn(a, b);
    return __builtin_bit_cast(unsigned int, h);
}

__device__ __forceinline__ float waveReduceSum(float v) {
    #pragma unroll
    for (int off = 32; off > 0; off >>= 1) v += __shfl_xor(v, off, 64);
    return v;
}

// ---------------- init: zero deg, sums, cnts ----------------
__global__ void init_kernel(int* deg, float* sums, float* cnts, int N, int G) {
    int i = blockIdx.x * 256 + threadIdx.x;
    if (i < N) deg[i] = 0;
    if (i < G * 128) sums[i] = 0.f;
    if (i < G) cnts[i] = 0.f;
}

// ---------------- precompute folded attention vectors ----------------
// wa1[h*32+c] = sum_o W1[h][c][o]*a_src1[h][o]  (wd1 with a_dst1); wa2/wd2 for layer 2.
__global__ __launch_bounds__(256) void precompute_kernel(
        const float* __restrict__ W1, const float* __restrict__ as1, const float* __restrict__ ad1,
        const float* __restrict__ W2, const float* __restrict__ as2, const float* __restrict__ ad2,
        float* __restrict__ wa1, float* __restrict__ wd1,
        float* __restrict__ wa2, float* __restrict__ wd2) {
    int t = threadIdx.x;
    if (t < 64) {                      // layer1: h=t>>5, c=t&31
        int h = t >> 5, c = t & 31;
        const float* w = W1 + (h * 32 + c) * 64;
        float sa = 0.f, sd = 0.f;
        for (int o = 0; o < 64; ++o) {
            sa = fmaf(w[o], as1[h * 64 + o], sa);
            sd = fmaf(w[o], ad1[h * 64 + o], sd);
        }
        wa1[t] = sa; wd1[t] = sd;
    } else if (t < 192) {              // layer2: u=t-64, h=u>>6, c=u&63
        int u = t - 64, h = u >> 6, c = u & 63;
        const float* w = W2 + (h * 64 + c) * 128;
        float sa = 0.f, sd = 0.f;
        for (int o = 0; o < 128; ++o) {
            sa = fmaf(w[o], as2[h * 128 + o], sa);
            sd = fmaf(w[o], ad2[h * 128 + o], sd);
        }
        wa2[u] = sa; wd2[u] = sd;
    }
}

// ---------------- CSR build ----------------
__global__ __launch_bounds__(256) void hist_kernel(const int* __restrict__ dst,
                                                   int* __restrict__ deg, int E) {
    int e = blockIdx.x * 256 + threadIdx.x;
    if (e < E) atomicAdd(&deg[dst[e]], 1);
}

__global__ __launch_bounds__(256) void scan_blocks_kernel(const int* __restrict__ deg,
        int* __restrict__ ofs, int* __restrict__ bsum, int N) {
    __shared__ int wtot[4];
    int tid = threadIdx.x, lane = tid & 63, wid = tid >> 6;
    int i = blockIdx.x * 256 + tid;
    int v = (i < N) ? deg[i] : 0;
    int incl = v;
    #pragma unroll
    for (int off = 1; off < 64; off <<= 1) {
        int t = __shfl_up(incl, off, 64);
        if (lane >= off) incl += t;
    }
    if (lane == 63) wtot[wid] = incl;
    __syncthreads();
    int woff = 0;
    #pragma unroll
    for (int w = 0; w < 4; ++w) if (w < wid) woff += wtot[w];
    int excl = incl - v + woff;
    if (i < N) ofs[i] = excl;
    if (tid == 255) bsum[blockIdx.x] = woff + incl;
}

__global__ __launch_bounds__(1024) void scan_bsum_kernel(const int* __restrict__ bsum,
        int* __restrict__ bofs, int* __restrict__ ofsN, int nb) {
    __shared__ int wsum[16];
    int tid = threadIdx.x, lane = tid & 63, wid = tid >> 6;
    int v = (tid < nb) ? bsum[tid] : 0;
    int incl = v;
    #pragma unroll
    for (int off = 1; off < 64; off <<= 1) {
        int t = __shfl_up(incl, off, 64);
        if (lane >= off) incl += t;
    }
    if (lane == 63) wsum[wid] = incl;
    __syncthreads();
    if (wid == 0) {
        int wv = (lane < 16) ? wsum[lane] : 0;
        int winc = wv;
        #pragma unroll
        for (int off = 1; off < 16; off <<= 1) {
            int t = __shfl_up(winc, off, 64);
            if (lane >= off) winc += t;
        }
        if (lane < 16) wsum[lane] = winc - wv;
    }
    __syncthreads();
    int excl = incl - v + wsum[wid];
    if (tid < nb) bofs[tid] = excl;
    if (tid == nb - 1) *ofsN = excl + v;
}

__global__ __launch_bounds__(256) void scan_add_kernel(int* __restrict__ ofs,
        const int* __restrict__ bofs, int* __restrict__ cursor, int N) {
    int i = blockIdx.x * 256 + threadIdx.x;
    if (i < N) {
        int v = ofs[i] + bofs[blockIdx.x];
        ofs[i] = v;
        cursor[i] = v;
    }
}

__global__ __launch_bounds__(256) void scatter_kernel(
        const int* __restrict__ src, const int* __restrict__ dst,
        int* __restrict__ cursor, int* __restrict__ sperm, int E) {
    int e = blockIdx.x * 256 + threadIdx.x;
    if (e >= E) return;
    int d = dst[e];
    int pos = atomicAdd(&cursor[d], 1);
    sperm[pos] = src[e];
}

// ---------------- fused fc0 + GAT layer1 transform (no reductions) ----------------
// h0 = elu(x@W0+b0) in LDS; h1 fp16 packed (half idx n*128 + 2*o + h);
// es/ed via folded vectors: es[n,h] = hs[n,:]·wa1[h,:]
__global__ __launch_bounds__(256) void fused_t1(
        const float* __restrict__ x, const float* __restrict__ w0,
        const float* __restrict__ b0, const float* __restrict__ W1,
        const float* __restrict__ wa1, const float* __restrict__ wd1,
        __half* __restrict__ h1, float* __restrict__ es, float* __restrict__ ed, int N) {
    __shared__ float xs[8 * 16];
    __shared__ float hs[8 * 32];
    int n0 = blockIdx.x * 8;
    int tid = threadIdx.x;
    if (tid < 128) {
        int gi = n0 * 16 + tid;
        xs[tid] = (gi < N * 16) ? x[gi] : 0.f;
    }
    __syncthreads();
    {
        int j = tid >> 5, o = tid & 31;
        float acc = b0[o];
        #pragma unroll
        for (int c = 0; c < 16; ++c) acc = fmaf(xs[j * 16 + c], w0[c * 32 + o], acc);
        hs[j * 32 + o] = elu_f(acc);
    }
    __syncthreads();
    int o = tid & 63, h = (tid >> 6) & 1, nh = tid >> 7;
    float acc[4];
    #pragma unroll
    for (int j = 0; j < 4; ++j) acc[j] = 0.f;
    const float* wp = W1 + h * (32 * 64) + o;
    #pragma unroll
    for (int c = 0; c < 32; ++c) {
        float wv = wp[c * 64];
        #pragma unroll
        for (int j = 0; j < 4; ++j) acc[j] = fmaf(hs[(nh * 4 + j) * 32 + c], wv, acc[j]);
    }
    #pragma unroll
    for (int j = 0; j < 4; ++j) {
        int n = n0 + nh * 4 + j;
        if (n < N) h1[(size_t)n * 128 + 2 * o + h] = __float2half(acc[j]);
    }
    // es/ed: 32 threads, each one (node, head, src/dst) dot of length 32
    if (tid < 32) {
        int n = tid >> 2, r = tid & 3, hh = r >> 1, isd = r & 1;
        const float* wv = (isd ? wd1 : wa1) + hh * 32;
        float s = 0.f;
        #pragma unroll
        for (int c = 0; c < 32; ++c) s = fmaf(hs[n * 32 + c], wv[c], s);
        int nn = n0 + n;
        if (nn < N) { if (isd) ed[nn * 2 + hh] = s; else es[nn * 2 + hh] = s; }
    }
}

// ---------------- GAT layer2 transform: h2 = g1 @ W2 (g1 pre-activated), no reductions ----------------
__global__ __launch_bounds__(256) void gat_transform2(
        const float* __restrict__ g1, const float* __restrict__ W,
        const float* __restrict__ wa2, const float* __restrict__ wd2,
        __half* __restrict__ h2, float* __restrict__ es, float* __restrict__ ed, int N) {
    __shared__ float xs[8 * 64];
    int n0 = blockIdx.x * 8;
    int tid = threadIdx.x;
    for (int idx = tid; idx < 8 * 64; idx += 256) {
        int gi = n0 * 64 + idx;
        xs[idx] = (gi < N * 64) ? g1[gi] : 0.f;
    }
    __syncthreads();
    int h = tid >> 7, o = tid & 127;
    float acc[8];
    #pragma unroll
    for (int j = 0; j < 8; ++j) acc[j] = 0.f;
    const float* wp = W + h * (64 * 128) + o;
    for (int c = 0; c < 64; ++c) {
        float wv = wp[c * 128];
        #pragma unroll
        for (int j = 0; j < 8; ++j) acc[j] = fmaf(xs[j * 64 + c], wv, acc[j]);
    }
    #pragma unroll
    for (int j = 0; j < 8; ++j) {
        int n = n0 + j;
        if (n < N) h2[(size_t)n * 256 + 2 * o + h] = __float2half(acc[j]);
    }
    // es/ed: 32 threads, each one (node, head, src/dst) dot of length 64
    if (tid < 32) {
        int n = tid >> 2, r = tid & 3, hh = r >> 1, isd = r & 1;
        const float* wv = (isd ? wd2 : wa2) + hh * 64;
        float s = 0.f;
        #pragma unroll
        for (int c = 0; c < 64; ++c) s = fmaf(xs[n * 64 + c], wv[c], s);
        int nn = n0 + n;
        if (nn < N) { if (isd) ed[nn * 2 + hh] = s; else es[nn * 2 + hh] = s; }
    }
}

// ---------------- aggregation layer1: one wave per dst node ----------------
// h1 rows: 64 uint (half2 .x=head0,.y=head1). meta in LDS: (src, alpha-pack) per edge.
__global__ __launch_bounds__(256) void gat_agg1(
        const int* __restrict__ ofs, const int* __restrict__ sperm,
        const float* __restrict__ es, const float* __restrict__ ed,
        const unsigned int* __restrict__ h1, const float* __restrict__ b1,
        float* __restrict__ g1, int N) {
    __shared__ uint2 meta[4][64];
    int w = threadIdx.x >> 6;
    int d = blockIdx.x * 4 + w;
    if (d >= N) return;
    int lane = threadIdx.x & 63;
    int beg = ofs[d], end = ofs[d + 1];
    int deg = end - beg;
    float2 edv = *reinterpret_cast<const float2*>(ed + (size_t)d * 2);

    int s_f = 0;
    float e0f = neg_inf_f(), e1f = neg_inf_f();
    float m0 = neg_inf_f(), m1 = neg_inf_f();
    int i0 = beg + lane;
    if (i0 < end) {
        s_f = sperm[i0];
        float2 esv = *reinterpret_cast<const float2*>(es + (size_t)s_f * 2);
        e0f = lrelu_f(esv.x + edv.x);
        e1f = lrelu_f(esv.y + edv.y);
        m0 = e0f; m1 = e1f;
    }
    for (int i = i0 + 64; i < end; i += 64) {
        int s = sperm[i];
        float2 esv = *reinterpret_cast<const float2*>(es + (size_t)s * 2);
        m0 = fmaxf(m0, lrelu_f(esv.x + edv.x));
        m1 = fmaxf(m1, lrelu_f(esv.y + edv.y));
    }
    #pragma unroll
    for (int off = 32; off > 0; off >>= 1) {
        m0 = fmaxf(m0, __shfl_xor(m0, off, 64));
        m1 = fmaxf(m1, __shfl_xor(m1, off, 64));
    }
    float s0 = 0.f, s1 = 0.f;
    if (i0 < end) { s0 = __expf(e0f - m0); s1 = __expf(e1f - m1); }
    for (int i = i0 + 64; i < end; i += 64) {
        int s = sperm[i];
        float2 esv = *reinterpret_cast<const float2*>(es + (size_t)s * 2);
        s0 += __expf(lrelu_f(esv.x + edv.x) - m0);
        s1 += __expf(lrelu_f(esv.y + edv.y) - m1);
    }
    s0 = waveReduceSum(s0);
    s1 = waveReduceSum(s1);
    float r0 = 0.5f / (s0 + GAT_EPS), r1 = 0.5f / (s1 + GAT_EPS);
    int jmax = deg < 64 ? deg : 64;
    if (lane < jmax)
        meta[w][lane] = make_uint2((unsigned int)s_f,
                                   pack_half2(__expf(e0f - m0) * r0, __expf(e1f - m1) * r1));
    // wave-internal LDS write->read; compiler inserts lgkmcnt wait, no barrier needed

    float acc = 0.f;
    int j = 0;
    for (; j + 4 <= jmax; j += 4) {
        uint2 m0_ = meta[w][j + 0];
        uint2 m1_ = meta[w][j + 1];
        uint2 m2_ = meta[w][j + 2];
        uint2 m3_ = meta[w][j + 3];
        unsigned int v0 = h1[(size_t)m0_.x * 64 + lane];
        unsigned int v1 = h1[(size_t)m1_.x * 64 + lane];
        unsigned int v2 = h1[(size_t)m2_.x * 64 + lane];
        unsigned int v3 = h1[(size_t)m3_.x * 64 + lane];
        acc = fdot2f(v0, m0_.y, acc);
        acc = fdot2f(v1, m1_.y, acc);
        acc = fdot2f(v2, m2_.y, acc);
        acc = fdot2f(v3, m3_.y, acc);
    }
    for (; j < jmax; ++j) {
        uint2 m = meta[w][j];
        acc = fdot2f(h1[(size_t)m.x * 64 + lane], m.y, acc);
    }
    for (int i = beg + 64; i < end; ++i) {  // rare: deg > 64
        int s = sperm[i];
        float2 esv = *reinterpret_cast<const float2*>(es + (size_t)s * 2);
        float a0 = __expf(lrelu_f(esv.x + edv.x) - m0) * r0;
        float a1 = __expf(lrelu_f(esv.y + edv.y) - m1) * r1;
        acc = fdot2f(h1[(size_t)s * 64 + lane], pack_half2(a0, a1), acc);
    }
    g1[(size_t)d * 64 + lane] = elu_f(acc + b1[lane]);   // pre-activate for transform2
}

// ---------------- aggregation layer2: one wave per dst node, 2 channels/lane ----------------
__global__ __launch_bounds__(256) void gat_agg2(
        const int* __restrict__ ofs, const int* __restrict__ sperm,
        const float* __restrict__ es, const float* __restrict__ ed,
        const uint2* __restrict__ h2, const float* __restrict__ b2,
        float* __restrict__ g2, int N) {
    __shared__ uint2 meta[4][64];
    int w = threadIdx.x >> 6;
    int d = blockIdx.x * 4 + w;
    if (d >= N) return;
    int lane = threadIdx.x & 63;
    int beg = ofs[d], end = ofs[d + 1];
    int deg = end - beg;
    float2 edv = *reinterpret_cast<const float2*>(ed + (size_t)d * 2);

    int s_f = 0;
    float e0f = neg_inf_f(), e1f = neg_inf_f();
    float m0 = neg_inf_f(), m1 = neg_inf_f();
    int i0 = beg + lane;
    if (i0 < end) {
        s_f = sperm[i0];
        float2 esv = *reinterpret_cast<const float2*>(es + (size_t)s_f * 2);
        e0f = lrelu_f(esv.x + edv.x);
        e1f = lrelu_f(esv.y + edv.y);
        m0 = e0f; m1 = e1f;
    }
    for (int i = i0 + 64; i < end; i += 64) {
        int s = sperm[i];
        float2 esv = *reinterpret_cast<const float2*>(es + (size_t)s * 2);
        m0 = fmaxf(m0, lrelu_f(esv.x + edv.x));
        m1 = fmaxf(m1, lrelu_f(esv.y + edv.y));
    }
    #pragma unroll
    for (int off = 32; off > 0; off >>= 1) {
        m0 = fmaxf(m0, __shfl_xor(m0, off, 64));
        m1 = fmaxf(m1, __shfl_xor(m1, off, 64));
    }
    float s0 = 0.f, s1 = 0.f;
    if (i0 < end) { s0 = __expf(e0f - m0); s1 = __expf(e1f - m1); }
    for (int i = i0 + 64; i < end; i += 64) {
        int s = sperm[i];
        float2 esv = *reinterpret_cast<const float2*>(es + (size_t)s * 2);
        s0 += __expf(lrelu_f(esv.x + edv.x) - m0);
        s1 += __expf(lrelu_f(esv.y + edv.y) - m1);
    }
    s0 = waveReduceSum(s0);
    s1 = waveReduceSum(s1);
    float r0 = 0.5f / (s0 + GAT_EPS), r1 = 0.5f / (s1 + GAT_EPS);
    int jmax = deg < 64 ? deg : 64;
    if (lane < jmax)
        meta[w][lane] = make_uint2((unsigned int)s_f,
                                   pack_half2(__expf(e0f - m0) * r0, __expf(e1f - m1) * r1));

    float acc0 = 0.f, acc1 = 0.f;   // channels 2*lane, 2*lane+1
    int j = 0;
    for (; j + 4 <= jmax; j += 4) {
        uint2 m0_ = meta[w][j + 0];
        uint2 m1_ = meta[w][j + 1];
        uint2 m2_ = meta[w][j + 2];
        uint2 m3_ = meta[w][j + 3];
        uint2 v0 = h2[(size_t)m0_.x * 64 + lane];
        uint2 v1 = h2[(size_t)m1_.x * 64 + lane];
        uint2 v2 = h2[(size_t)m2_.x * 64 + lane];
        uint2 v3 = h2[(size_t)m3_.x * 64 + lane];
        acc0 = fdot2f(v0.x, m0_.y, acc0); acc1 = fdot2f(v0.y, m0_.y, acc1);
        acc0 = fdot2f(v1.x, m1_.y, acc0); acc1 = fdot2f(v1.y, m1_.y, acc1);
        acc0 = fdot2f(v2.x, m2_.y, acc0); acc1 = fdot2f(v2.y, m2_.y, acc1);
        acc0 = fdot2f(v3.x, m3_.y, acc0); acc1 = fdot2f(v3.y, m3_.y, acc1);
    }
    for (; j < jmax; ++j) {
        uint2 m = meta[w][j];
        uint2 v = h2[(size_t)m.x * 64 + lane];
        acc0 = fdot2f(v.x, m.y, acc0);
        acc1 = fdot2f(v.y, m.y, acc1);
    }
    for (int i = beg + 64; i < end; ++i) {  // rare: deg > 64
        int s = sperm[i];
        float2 esv = *reinterpret_cast<const float2*>(es + (size_t)s * 2);
        float a0 = __expf(lrelu_f(esv.x + edv.x) - m0) * r0;
        float a1 = __expf(lrelu_f(esv.y + edv.y) - m1) * r1;
        unsigned int ap = pack_half2(a0, a1);
        uint2 v = h2[(size_t)s * 64 + lane];
        acc0 = fdot2f(v.x, ap, acc0);
        acc1 = fdot2f(v.y, ap, acc1);
    }
    float2 bv = reinterpret_cast<const float2*>(b2)[lane];
    g2[(size_t)d * 128 + 2 * lane]     = elu_f(acc0 + bv.x);   // pre-activated for pool
    g2[(size_t)d * 128 + 2 * lane + 1] = elu_f(acc1 + bv.y);
}

// ---------------- pool: sorted-batch run accumulation (g2 pre-activated) ----------------
#define POOL_NPB 128
__global__ __launch_bounds__(256) void pool_kernel(
        const float* __restrict__ g2, const int* __restrict__ batch,
        float* __restrict__ sums, float* __restrict__ cnts, int N) {
    int n0 = blockIdx.x * POOL_NPB;
    int c = threadIdx.x & 127;
    int p = threadIdx.x >> 7;
    int nend = n0 + POOL_NPB; if (nend > N) nend = N;
    int n = n0 + p;
    if (n >= nend) return;
    int cur_b = batch[n];
    float acc = 0.f;
    int cnt = 0;
    for (; n < nend; n += 2) {
        int b = batch[n];
        if (b != cur_b) {
            atomicAdd(&sums[(size_t)cur_b * 128 + c], acc);
            if (c == 0) atomicAdd(&cnts[cur_b], (float)cnt);
            acc = 0.f; cnt = 0; cur_b = b;
        }
        acc += g2[(size_t)n * 128 + c];
        ++cnt;
    }
    atomicAdd(&sums[(size_t)cur_b * 128 + c], acc);
    if (c == 0) atomicAdd(&cnts[cur_b], (float)cnt);
}

// ---------------- final: out = (sums/cnt) @ lo_w + lo_b ----------------
__global__ void final_kernel(
        const float* __restrict__ sums, const float* __restrict__ cnts,
        const float* __restrict__ w, const float* __restrict__ b,
        float* __restrict__ out, int G) {
    int g = blockIdx.x;
    int k = threadIdx.x;
    if (k >= 24) return;
    float inv = 1.f / fmaxf(cnts[g], 1.f);
    float acc = b[k];
    #pragma unroll
    for (int c = 0; c < 128; ++c) acc = fmaf(sums[g * 128 + c] * inv, w[c * 24 + k], acc);
    out[g * 24 + k] = acc;
}

extern "C" void kernel_launch(void* const* d_in, const int* in_sizes, int n_in,
                              void* d_out, int out_size, void* d_ws, size_t ws_size,
                              hipStream_t stream) {
    const float* x      = (const float*)d_in[0];
    const int*   ei     = (const int*)d_in[1];
    const int*   batch  = (const int*)d_in[2];
    const float* fc0_w  = (const float*)d_in[3];
    const float* fc0_b  = (const float*)d_in[4];
    const float* W1     = (const float*)d_in[5];
    const float* a_src1 = (const float*)d_in[6];
    const float* a_dst1 = (const float*)d_in[7];
    const float* b1     = (const float*)d_in[8];
    const float* W2     = (const float*)d_in[9];
    const float* a_src2 = (const float*)d_in[10];
    const float* a_dst2 = (const float*)d_in[11];
    const float* b2     = (const float*)d_in[12];
    const float* lo_w   = (const float*)d_in[13];
    const float* lo_b   = (const float*)d_in[14];
    float* out = (float*)d_out;

    const int N = in_sizes[0] / 16;
    const int E = in_sizes[1] / 2;
    const int G = out_size / 24;
    const int* src = ei;
    const int* dst = ei + E;
    const int nb = (N + 255) / 256;

    char* wsb = (char*)d_ws;
    size_t off = 0;
    auto allocf = [&](size_t n) { float* p = (float*)(wsb + off); off += ((n * 4 + 255) & ~(size_t)255); return p; };
    auto alloci = [&](size_t n) { int* p = (int*)(wsb + off); off += ((n * 4 + 255) & ~(size_t)255); return p; };
    auto alloch = [&](size_t n) { __half* p = (__half*)(wsb + off); off += ((n * 2 + 255) & ~(size_t)255); return p; };
    __half* hbuf  = alloch((size_t)N * 256);   // h1 uses N*128 halves; h2 uses N*256 halves
    float*  g1    = allocf((size_t)N * 64);
    float*  g2    = allocf((size_t)N * 128);
    float*  es    = allocf((size_t)N * 2);
    float*  ed    = allocf((size_t)N * 2);
    float*  sums  = allocf((size_t)G * 128);
    float*  cnts  = allocf((size_t)G);
    float*  wa1   = allocf(64);
    float*  wd1   = allocf(64);
    float*  wa2   = allocf(128);
    float*  wd2   = allocf(128);
    int* deg     = alloci((size_t)N);
    int* ofs     = alloci((size_t)N + 1);
    int* cursor  = alloci((size_t)N);
    int* sperm   = alloci((size_t)E);
    int* bsum    = alloci((size_t)nb);
    int* bofs    = alloci((size_t)nb);
    (void)ws_size;

    // init + folded attention vectors + CSR build
    init_kernel<<<(N + 255) / 256, 256, 0, stream>>>(deg, sums, cnts, N, G);
    precompute_kernel<<<1, 256, 0, stream>>>(W1, a_src1, a_dst1, W2, a_src2, a_dst2,
                                             wa1, wd1, wa2, wd2);
    hist_kernel<<<(E + 255) / 256, 256, 0, stream>>>(dst, deg, E);
    scan_blocks_kernel<<<nb, 256, 0, stream>>>(deg, ofs, bsum, N);
    scan_bsum_kernel<<<1, 1024, 0, stream>>>(bsum, bofs, ofs + N, nb);
    scan_add_kernel<<<nb, 256, 0, stream>>>(ofs, bofs, cursor, N);
    scatter_kernel<<<(E + 255) / 256, 256, 0, stream>>>(src, dst, cursor, sperm, E);

    // ---- GAT layer 1 (fc0 fused into transform) ----
    fused_t1<<<(N + 7) / 8, 256, 0, stream>>>(x, fc0_w, fc0_b, W1, wa1, wd1, hbuf, es, ed, N);
    gat_agg1<<<(N + 3) / 4, 256, 0, stream>>>(ofs, sperm, es, ed, (const unsigned int*)hbuf, b1, g1, N);

    // ---- GAT layer 2 ----
    gat_transform2<<<(N + 7) / 8, 256, 0, stream>>>(g1, W2, wa2, wd2, hbuf, es, ed, N);
    gat_agg2<<<(N + 3) / 4, 256, 0, stream>>>(ofs, sperm, es, ed, (const uint2*)hbuf, b2, g2, N);

    // ---- pool + final linear ----
    pool_kernel<<<(N + POOL_NPB - 1) / POOL_NPB, 256, 0, stream>>>(g2, batch, sums, cnts, N);
    final_kernel<<<G, 32, 0, stream>>>(sums, cnts, lo_w, lo_b, out, G);
}